// Round 11
// baseline (1451.918 us; speedup 1.0000x reference)
//
#include <hip/hip_runtime.h>
#include <hip/hip_bf16.h>
#include <math.h>

#define LRELU 0.01f
#define GB 1024   // persistent grid: 4 blocks/CU x 256 CUs, co-resident

// ---------------- grid barrier (device-scope, sense via generation) --------
__device__ __forceinline__ void gsync(unsigned* cnt, unsigned* gen) {
    __syncthreads();
    if (threadIdx.x == 0) {
        __threadfence();
        unsigned g = __hip_atomic_load(gen, __ATOMIC_RELAXED, __HIP_MEMORY_SCOPE_AGENT);
        unsigned a = __hip_atomic_fetch_add(cnt, 1u, __ATOMIC_ACQ_REL, __HIP_MEMORY_SCOPE_AGENT);
        if (a + 1u == (unsigned)GB) {
            __hip_atomic_store(cnt, 0u, __ATOMIC_RELAXED, __HIP_MEMORY_SCOPE_AGENT);
            __hip_atomic_fetch_add(gen, 1u, __ATOMIC_RELEASE, __HIP_MEMORY_SCOPE_AGENT);
        } else {
            int guard = 0;
            while (__hip_atomic_load(gen, __ATOMIC_RELAXED, __HIP_MEMORY_SCOPE_AGENT) == g) {
                __builtin_amdgcn_s_sleep(2);
                if (++guard > (1 << 24)) break;   // bail, no hang
            }
        }
        __threadfence();
    }
    __syncthreads();
}

// ---------------- vectorized LDS weight fetch ----------------
template<int CO_BLK>
__device__ __forceinline__ void ldw(const float* p, float* w) {
    if constexpr (CO_BLK % 4 == 0) {
#pragma unroll
        for (int u = 0; u < CO_BLK / 4; u++) {
            float4 v = *(const float4*)(p + 4 * u);
            w[4*u] = v.x; w[4*u+1] = v.y; w[4*u+2] = v.z; w[4*u+3] = v.w;
        }
    } else {
#pragma unroll
        for (int c = 0; c < CO_BLK; c++) w[c] = p[c];
    }
}

// ---------------- prep element ----------------
__device__ __forceinline__ void wfwd(const float* s, float* d, int CIN, int COUT,
                                     int KK, int i) {
    int co = i / (CIN * KK); int r = i - co * CIN * KK;
    int ci = r / KK; int t = r - ci * KK;
    d[(ci * KK + t) * COUT + co] = s[i];
}
__device__ __forceinline__ void wtr(const float* s, float* d, int CIN, int COUT,
                                    int KK, int i) {
    int ci = i / (COUT * KK); int r = i - ci * COUT * KK;
    int co = r / KK; int t = r - co * KK;
    d[(t * CIN + ci) * COUT + co] = s[i];
}
__device__ __forceinline__ void prep_elem(int i, const float* e1, const float* e2,
        const float* e3, const float* e4, const float* e5, const float* d1,
        const float* d2, const float* d3, const float* d4, float* w,
        const float* cbp, float* hcbn, unsigned long long* keys, float* loss) {
    if      (i < 128)   wfwd(e1, w + 0,     1,  8, 16, i);
    else if (i < 2176)  wfwd(e2, w + 128,   8, 16, 16, i - 128);
    else if (i < 10368) wfwd(e3, w + 2176, 16, 32, 16, i - 2176);
    else if (i < 19584) wfwd(e4, w + 10368, 32, 32, 9, i - 10368);
    else if (i < 21632) wfwd(e5, w + 19584, 32, 64, 1, i - 19584);
    else if (i < 40064) wfwd(d1, w + 21632, 64, 32, 9, i - 21632);
    else if (i < 48256) wtr (d2, w + 40064, 32, 16, 16, i - 40064);
    else if (i < 50304) wtr (d3, w + 48256, 16,  8, 16, i - 48256);
    else if (i < 50432) wtr (d4, w + 50304,  8,  1, 16, i - 50304);
    else if (i < 50944) {
        int k = i - 50432;
        const float* c = cbp + k * 64;
        float s = 0.f;
#pragma unroll
        for (int d = 0; d < 64; d++) s = fmaf(c[d], c[d], s);
        hcbn[k] = 0.5f * s;
    } else if (i < 50944 + 57600) {
        keys[i - 50944] = 0xFFFFFFFFFFFFFFFFull;
    } else if (i == 50944 + 57600) {
        loss[0] = 0.f;
    }
}

// ---------------- zero elements ----------------
__device__ __forceinline__ void zframeA_elem(int j, float* a) {   // [64,32,32,32]
    int pl = j / 124, s = j - pl * 124;
    int r, c;
    if (s < 32)      { r = 0;  c = s; }
    else if (s < 64) { r = 31; c = s - 32; }
    else { int u = s - 64; r = 1 + (u >> 1); c = (u & 1) * 31; }
    a[(size_t)pl * 1024 + r * 32 + c] = 0.f;
}
__device__ __forceinline__ void zframeZ_elem(int j, float* zb) {  // [64,64,32,32]
    int pl = j / 124, s = j - pl * 124;
    int r, c;
    if (s < 32)      { r = 0;  c = s; }
    else if (s < 64) { r = 31; c = s - 32; }
    else { int u = s - 64; r = 1 + (u >> 1); c = (u & 1) * 31; }
    zb[(size_t)pl * 1024 + r * 32 + c] = 0.f;
}
__device__ __forceinline__ void zsB_elem(int i, float* d2o) {     // [64,16,63,66]
    int pl = i / 189, u = i - pl * 189;
    int r = u / 3, c3 = u - r * 3;
    int col = (c3 == 0) ? 0 : 63 + c3;
    d2o[((size_t)pl * 63 + r) * 66 + col] = 0.f;
}
__device__ __forceinline__ void zsA_elem(int i, float* d3o) {     // [64,8,129,132]
    int pl = i / 387, u = i - pl * 387;
    int r = u / 3, c3 = u - r * 3;
    int col = (c3 == 0) ? 0 : 129 + c3;
    d3o[((size_t)pl * 129 + r) * 132 + col] = 0.f;
}

// ---------------- k4 s2 forward conv body ----------------
template<int CIN, int COUT, int CO_BLK, int HIN, int ISTR, int HOUT, int WOUT,
         int OPLANE, int OSTR, int OPAD, int CB, int RB>
__device__ void convs2_body(int b, int tz, float* lw,
                            const float* __restrict__ in, const float* __restrict__ wt,
                            const float* __restrict__ bias, float* __restrict__ out) {
    const int tid = threadIdx.x;
    __syncthreads();
    for (int i = tid; i < CIN * 16 * CO_BLK; i += 256) {
        int row = i / CO_BLK, c = i - row * CO_BLK;
        lw[i] = wt[row * COUT + (0) + c];    // cog folded below
    }
    // NOTE: cog must be part of address; re-stage with cog:
    __syncthreads();
    (void)0;
    // (cog handled by caller passing wt already offset)
    const int cbi = tz / RB, rb = tz - cbi * RB;
    const int tx = tid & 15, ty = tid >> 4;
    const int ow0 = (cbi * 16 + tx) * 2;
    const int oh  = rb * 16 + ty;
    if (oh < HOUT && ow0 < WOUT) {
        const bool p1v = (ow0 + 1) < WOUT;
        float acc[CO_BLK][2];
#pragma unroll
        for (int c = 0; c < CO_BLK; c++) {
            float bv = bias[c];
            acc[c][0] = bv; acc[c][1] = bv;
        }
        const float* inb = in + ((size_t)(b * CIN) * HIN + oh * 2) * ISTR + ow0 * 2;
#pragma unroll 2
        for (int ci = 0; ci < CIN; ci++) {
            const float* r = inb + (size_t)ci * HIN * ISTR;
            float4 a4[4]; float2 b2[4];
#pragma unroll
            for (int kh = 0; kh < 4; kh++) {
                a4[kh] = *(const float4*)(r + kh * ISTR);
                b2[kh] = p1v ? *(const float2*)(r + kh * ISTR + 4) : make_float2(0.f, 0.f);
            }
            const float* wr = lw + ci * 16 * CO_BLK;
#pragma unroll
            for (int kh = 0; kh < 4; kh++) {
                float x0[4] = {a4[kh].x, a4[kh].y, a4[kh].z, a4[kh].w};
                float x1[4] = {a4[kh].z, a4[kh].w, b2[kh].x, b2[kh].y};
#pragma unroll
                for (int kw = 0; kw < 4; kw++) {
                    float wv[CO_BLK];
                    ldw<CO_BLK>(wr + (kh * 4 + kw) * CO_BLK, wv);
#pragma unroll
                    for (int c = 0; c < CO_BLK; c++) {
                        acc[c][0] = fmaf(x0[kw], wv[c], acc[c][0]);
                        acc[c][1] = fmaf(x1[kw], wv[c], acc[c][1]);
                    }
                }
            }
        }
        float* ob = out + (size_t)(b * COUT) * OPLANE
                        + (oh + OPAD) * OSTR + ow0 + OPAD;
#pragma unroll
        for (int c = 0; c < CO_BLK; c++) {
            float v0 = acc[c][0]; v0 = (v0 >= 0.f) ? v0 : LRELU * v0;
            ob[(size_t)c * OPLANE] = v0;
            if (p1v) {
                float v1 = acc[c][1]; v1 = (v1 >= 0.f) ? v1 : LRELU * v1;
                ob[(size_t)c * OPLANE + 1] = v1;
            }
        }
    }
}

// ---------------- k3 s1 p1 conv body (padded [*,C,32,32] in) ----------------
template<int CIN, int COUT, int CO_BLK, int OPLANE, int OSTR, int OPADH, int OPADV,
         bool ZSIDE>
__device__ void conv3_body(int b, int cog, int rb, float* lw,
                           const float* __restrict__ in, const float* __restrict__ wt,
                           const float* __restrict__ bias, float* __restrict__ out) {
    const int tid = threadIdx.x;
    __syncthreads();
    for (int i = tid; i < CIN * 9 * CO_BLK; i += 256) {
        int row = i / CO_BLK, c = i - row * CO_BLK;
        lw[i] = wt[row * COUT + cog * CO_BLK + c];
    }
    __syncthreads();
    const int tx = tid & 15, ty = tid >> 4;
    const int r = rb * 16 + ty;
    if (r < 30) {
        if (tx == 15) {
            if (ZSIDE) {
#pragma unroll
                for (int c = 0; c < CO_BLK; c++) {
                    float* base = out + (size_t)(b * COUT + cog * CO_BLK + c) * OPLANE
                                      + (r + OPADV) * OSTR;
                    base[0] = 0.f; base[31] = 0.f; base[32] = 0.f;
                }
            }
        } else {
            const int ow0 = tx * 2;
            float acc[CO_BLK][2];
#pragma unroll
            for (int c = 0; c < CO_BLK; c++) {
                float bv = bias[cog * CO_BLK + c];
                acc[c][0] = bv; acc[c][1] = bv;
            }
            const float* inb = in + ((size_t)(b * CIN) * 32 + r) * 32 + ow0;
#pragma unroll 2
            for (int ci = 0; ci < CIN; ci++) {
                const float* rr = inb + (size_t)ci * 1024;
                float2 A[3], Bv[3];
#pragma unroll
                for (int kh = 0; kh < 3; kh++) {
                    A[kh]  = *(const float2*)(rr + kh * 32);
                    Bv[kh] = *(const float2*)(rr + kh * 32 + 2);
                }
                const float* wr = lw + ci * 9 * CO_BLK;
#pragma unroll
                for (int kh = 0; kh < 3; kh++) {
                    float x0[3] = {A[kh].x, A[kh].y, Bv[kh].x};
                    float x1[3] = {A[kh].y, Bv[kh].x, Bv[kh].y};
#pragma unroll
                    for (int kw = 0; kw < 3; kw++) {
                        float wv[CO_BLK];
                        ldw<CO_BLK>(wr + (kh * 3 + kw) * CO_BLK, wv);
#pragma unroll
                        for (int c = 0; c < CO_BLK; c++) {
                            acc[c][0] = fmaf(x0[kw], wv[c], acc[c][0]);
                            acc[c][1] = fmaf(x1[kw], wv[c], acc[c][1]);
                        }
                    }
                }
            }
            float* ob = out + (size_t)(b * COUT + cog * CO_BLK) * OPLANE
                            + (r + OPADV) * OSTR + ow0 + OPADH;
#pragma unroll
            for (int c = 0; c < CO_BLK; c++) {
                float v0 = acc[c][0]; v0 = (v0 >= 0.f) ? v0 : LRELU * v0;
                float v1 = acc[c][1]; v1 = (v1 >= 0.f) ? v1 : LRELU * v1;
                ob[(size_t)c * OPLANE] = v0;
                ob[(size_t)c * OPLANE + 1] = v1;
            }
        }
    }
}

// ---------------- 1x1 conv body ----------------
template<int CIN, int COUT, int CO_BLK>
__device__ void conv1_body(int b, int cog, float* lw,
                           const float* __restrict__ in, const float* __restrict__ wt,
                           const float* __restrict__ bias, float* __restrict__ out) {
    const int tid = threadIdx.x;
    __syncthreads();
    for (int i = tid; i < CIN * CO_BLK; i += 256) {
        int row = i / CO_BLK, c = i - row * CO_BLK;
        lw[i] = wt[row * COUT + cog * CO_BLK + c];
    }
    __syncthreads();
    const int px4 = tid * 4;
    float acc[CO_BLK][4];
#pragma unroll
    for (int c = 0; c < CO_BLK; c++) {
        float bv = bias[cog * CO_BLK + c];
        acc[c][0] = bv; acc[c][1] = bv; acc[c][2] = bv; acc[c][3] = bv;
    }
#pragma unroll 4
    for (int ci = 0; ci < CIN; ci++) {
        float4 x = *(const float4*)(in + (size_t)(b * CIN + ci) * 1024 + px4);
        float wv[CO_BLK];
        ldw<CO_BLK>(lw + ci * CO_BLK, wv);
#pragma unroll
        for (int c = 0; c < CO_BLK; c++) {
            acc[c][0] = fmaf(x.x, wv[c], acc[c][0]);
            acc[c][1] = fmaf(x.y, wv[c], acc[c][1]);
            acc[c][2] = fmaf(x.z, wv[c], acc[c][2]);
            acc[c][3] = fmaf(x.w, wv[c], acc[c][3]);
        }
    }
#pragma unroll
    for (int c = 0; c < CO_BLK; c++) {
        float4 v;
        v.x = (acc[c][0] >= 0.f) ? acc[c][0] : LRELU * acc[c][0];
        v.y = (acc[c][1] >= 0.f) ? acc[c][1] : LRELU * acc[c][1];
        v.z = (acc[c][2] >= 0.f) ? acc[c][2] : LRELU * acc[c][2];
        v.w = (acc[c][3] >= 0.f) ? acc[c][3] : LRELU * acc[c][3];
        *(float4*)(out + (size_t)(b * COUT + cog * CO_BLK + c) * 1024 + px4) = v;
    }
}

// ---------------- convT k4 s2 body ----------------
template<int CIN, int COUT, int CO_BLK, int HIN, int ISTR, int HOUT, int WOUT,
         int OPLANE, int OSTR, int OPADH, int TX, int CB, int RB, bool DO_TANH>
__device__ void convt2_body(int b, int cog, int tz, float* lw,
                            const float* __restrict__ in, const float* __restrict__ wt,
                            const float* __restrict__ bias, float* __restrict__ out) {
    const int tid = threadIdx.x;
    const int cls = tz / (CB * RB);
    const int rem = tz - cls * (CB * RB);
    const int cb = rem / RB, rb = rem - cb * RB;
    const int py = cls & 1, px = cls >> 1;

    __syncthreads();
    for (int i = tid; i < 4 * CIN * CO_BLK; i += 256) {
        int aq = i / (CIN * CO_BLK); int rr2 = i - aq * CIN * CO_BLK;
        int ci = rr2 / CO_BLK; int c = rr2 - ci * CO_BLK;
        int a = aq >> 1, q = aq & 1;
        int tap = (py + 2 * a) * 4 + px + 2 * q;
        lw[i] = wt[(tap * CIN + ci) * COUT + cog * CO_BLK + c];
    }
    __syncthreads();

    const int H2 = (HOUT - py + 1) >> 1;
    const int W2 = (WOUT - px + 1) >> 1;
    const int TY = 256 / TX;
    const int tx = tid % TX, ty = tid / TX;
    const int o0 = (cb * TX + tx) * 2;
    const int oh2 = rb * TY + ty;
    if (oh2 < H2 && o0 < W2) {
        const bool p1v = (o0 + 1) < W2;
        float acc[CO_BLK][2];
#pragma unroll
        for (int c = 0; c < CO_BLK; c++) {
            float bv = bias[cog * CO_BLK + c];
            acc[c][0] = bv; acc[c][1] = bv;
        }
#pragma unroll
        for (int a = 0; a < 2; a++) {
            int ih = oh2 - a;
            bool rv = (ih >= 0) && (ih < HIN);
            const float* rowp = in + ((size_t)(b * CIN) * HIN + ih) * ISTR + o0;
            const float* lw0 = lw + (a * 2 + 0) * CIN * CO_BLK;
            const float* lw1 = lw + (a * 2 + 1) * CIN * CO_BLK;
#pragma unroll 2
            for (int ci = 0; ci < CIN; ci++) {
                const float* p = rowp + (size_t)ci * HIN * ISTR;
                float2 A  = rv ? *(const float2*)p : make_float2(0.f, 0.f);
                float2 Bv = (rv && p1v) ? *(const float2*)(p + 2) : make_float2(0.f, 0.f);
                float w0[CO_BLK], w1[CO_BLK];
                ldw<CO_BLK>(lw0 + ci * CO_BLK, w0);
                ldw<CO_BLK>(lw1 + ci * CO_BLK, w1);
#pragma unroll
                for (int c = 0; c < CO_BLK; c++) {
                    acc[c][0] = fmaf(A.y, w0[c], acc[c][0]);
                    acc[c][0] = fmaf(A.x, w1[c], acc[c][0]);
                    acc[c][1] = fmaf(Bv.x, w0[c], acc[c][1]);
                    acc[c][1] = fmaf(A.y, w1[c], acc[c][1]);
                }
            }
        }
        const int oh = 2 * oh2 + py, ow = 2 * o0 + px;
        float* ob = out + (size_t)(b * COUT + cog * CO_BLK) * OPLANE + oh * OSTR + ow + OPADH;
#pragma unroll
        for (int c = 0; c < CO_BLK; c++) {
            float v0 = acc[c][0];
            if (!DO_TANH) v0 = (v0 >= 0.f) ? v0 : LRELU * v0; else v0 = tanhf(v0);
            ob[(size_t)c * OPLANE] = v0;
            if (p1v) {
                float v1 = acc[c][1];
                if (!DO_TANH) v1 = (v1 >= 0.f) ? v1 : LRELU * v1; else v1 = tanhf(v1);
                ob[(size_t)c * OPLANE + 2] = v1;
            }
        }
    }
}

// ---------------- VQ argmin body (R10 structure) ----------------
__device__ void vqargmin_body(int pb, int q, float* smem,
                              const float* __restrict__ lat, const float* __restrict__ cb,
                              const float* __restrict__ hcbn,
                              unsigned long long* __restrict__ keys) {
    float4* scb4 = (float4*)smem;
    float*  shn  = smem + 4096;
    const int tid = threadIdx.x;
    const int dq  = tid & 3;
    const int pg  = tid >> 2;
    const int kbase = q * 64;
    const int posbase = pb * 256;

    __syncthreads();
    const float4* src = (const float4*)(cb + (size_t)kbase * 64);
#pragma unroll
    for (int i = 0; i < 4; i++) scb4[tid + 256 * i] = src[tid + 256 * i];
    if (tid < 64) shn[tid] = hcbn[kbase + tid];

    float l[4][16];
    int   pidx[4];
#pragma unroll
    for (int j = 0; j < 4; j++) {
        int pos = posbase + pg + 64 * j;
        pidx[j] = pos;
        int b = pos / 900, p = pos - b * 900;
        int oh = p / 30, ow = p - oh * 30;
        int pp = 33 + oh * 32 + ow;
        const float* lb = lat + ((size_t)b * 64 + dq * 16) * 1024 + pp;
#pragma unroll
        for (int i = 0; i < 16; i++) l[j][i] = lb[i * 1024];
    }
    __syncthreads();

    float best[4] = {3.4e38f, 3.4e38f, 3.4e38f, 3.4e38f};
    int   bi[4]   = {0, 0, 0, 0};
#pragma unroll 2
    for (int k0 = 0; k0 < 64; k0++) {
        float4 c0 = scb4[k0 * 16 + dq * 4 + 0];
        float4 c1 = scb4[k0 * 16 + dq * 4 + 1];
        float4 c2 = scb4[k0 * 16 + dq * 4 + 2];
        float4 c3 = scb4[k0 * 16 + dq * 4 + 3];
        float hn = shn[k0];
#pragma unroll
        for (int j = 0; j < 4; j++) {
            float dot = 0.f;
            dot = fmaf(l[j][0],  c0.x, dot); dot = fmaf(l[j][1],  c0.y, dot);
            dot = fmaf(l[j][2],  c0.z, dot); dot = fmaf(l[j][3],  c0.w, dot);
            dot = fmaf(l[j][4],  c1.x, dot); dot = fmaf(l[j][5],  c1.y, dot);
            dot = fmaf(l[j][6],  c1.z, dot); dot = fmaf(l[j][7],  c1.w, dot);
            dot = fmaf(l[j][8],  c2.x, dot); dot = fmaf(l[j][9],  c2.y, dot);
            dot = fmaf(l[j][10], c2.z, dot); dot = fmaf(l[j][11], c2.w, dot);
            dot = fmaf(l[j][12], c3.x, dot); dot = fmaf(l[j][13], c3.y, dot);
            dot = fmaf(l[j][14], c3.z, dot); dot = fmaf(l[j][15], c3.w, dot);
            float full = dot + __shfl_xor(dot, 1);
            full += __shfl_xor(full, 2);
            float score = hn - full;
            if (score < best[j]) { best[j] = score; bi[j] = kbase + k0; }
        }
    }
    if (dq == 0) {
#pragma unroll
        for (int j = 0; j < 4; j++) {
            unsigned u = __float_as_uint(best[j]);
            u = ((int)u < 0) ? ~u : (u | 0x80000000u);
            unsigned long long key = ((unsigned long long)u << 32) | (unsigned)bi[j];
            atomicMin(&keys[pidx[j]], key);
        }
    }
}

// ---------------- VQ finalize body ----------------
__device__ void vqfin_body(int t, float* smem,
                           const float* __restrict__ lat, const float* __restrict__ cb,
                           const unsigned long long* __restrict__ keys,
                           float* __restrict__ z, float* __restrict__ loss_acc) {
    float* red = smem;
    const int tid = threadIdx.x;
    int gid = t * 256 + tid;
    int b = gid / 900, p = gid - b * 900;
    int oh = p / 30, ow = p - oh * 30;
    int pp = 33 + oh * 32 + ow;
    int idx = (int)(unsigned)(keys[gid] & 0xFFFFFFFFull);
    const float4* crow = (const float4*)(cb + (size_t)idx * 64);
    const float* lrow = lat + (size_t)b * 64 * 1024 + pp;
    float*       zrow = z   + (size_t)b * 64 * 1024 + pp;
    float myloss = 0.f;
#pragma unroll
    for (int i = 0; i < 16; i++) {
        float4 cv = crow[i];
        float lv0 = lrow[(4 * i + 0) * 1024];
        float lv1 = lrow[(4 * i + 1) * 1024];
        float lv2 = lrow[(4 * i + 2) * 1024];
        float lv3 = lrow[(4 * i + 3) * 1024];
        zrow[(4 * i + 0) * 1024] = cv.x;
        zrow[(4 * i + 1) * 1024] = cv.y;
        zrow[(4 * i + 2) * 1024] = cv.z;
        zrow[(4 * i + 3) * 1024] = cv.w;
        float d0 = cv.x - lv0, d1 = cv.y - lv1, d2 = cv.z - lv2, d3 = cv.w - lv3;
        myloss = fmaf(d0, d0, myloss);
        myloss = fmaf(d1, d1, myloss);
        myloss = fmaf(d2, d2, myloss);
        myloss = fmaf(d3, d3, myloss);
    }
    __syncthreads();
    red[tid] = myloss;
    __syncthreads();
    for (int s = 128; s > 0; s >>= 1) {
        if (tid < s) red[tid] += red[tid + s];
        __syncthreads();
    }
    if (tid == 0) atomicAdd(loss_acc, red[0]);
}

// ======================= the mega kernel =======================
__global__ __launch_bounds__(256, 4)
void mega_k(const float* x,
            const float* ew1, const float* eb1, const float* ew2, const float* eb2,
            const float* ew3, const float* eb3, const float* ew4, const float* eb4,
            const float* ew5, const float* eb5, const float* dw1, const float* db1,
            const float* dw2, const float* db2, const float* dw3, const float* db3,
            const float* dw4, const float* db4, const float* cb,
            float* out, int out_size,
            float* A, float* Bb, unsigned long long* keys, float* hcbn,
            float* loss, float* wtb, unsigned* cnt, unsigned* gen) {
    __shared__ __align__(16) float smem[4224];   // 16.9 KB, unioned per phase
    const int bx = blockIdx.x;
    const int tid = threadIdx.x;

    float* ew1t = wtb;          float* ew2t = wtb + 128;
    float* ew3t = wtb + 2176;   float* ew4t = wtb + 10368;
    float* ew5t = wtb + 19584;  float* dw1t = wtb + 21632;
    float* dw2t = wtb + 40064;  float* dw3t = wtb + 48256;
    float* dw4t = wtb + 50304;

    // P0: prep (weights, hcbn, keys, loss)
    for (int t = bx; t < 425; t += GB)
        prep_elem(t * 256 + tid, ew1, ew2, ew3, ew4, ew5, dw1, dw2, dw3, dw4,
                  wtb, cb, hcbn, keys, loss);
    gsync(cnt, gen);

    // P1: e1  x -> A [64,8,127,(128)]   tasks 2048
    for (int t = bx; t < 2048; t += GB) {
        int b = t & 63, tz = t >> 6;
        convs2_body<1, 8, 8, 256, 256, 127, 127, 127 * 128, 128, 0, 4, 8>(
            b, tz, smem, x, ew1t, eb1, A);
    }
    gsync(cnt, gen);

    // P2: e2  A -> Bb [64,16,62,(64)]   tasks 2048 (cog in [0,4), CO_BLK=4)
    for (int t = bx; t < 2048; t += GB) {
        int b = t & 63, r = t >> 6;
        int cog = r >> 3, tz = r & 7;
        convs2_body<8, 16, 4, 127, 128, 62, 62, 62 * 64, 64, 0, 2, 4>(
            b, tz, smem, A, ew2t + cog * 4, eb2 + cog * 4, Bb + (size_t)cog * 4 * 62 * 64);
    }
    gsync(cnt, gen);

    // P3: e3 (Bb -> A padded [64,32,32,32]) + zero A frames.   1024 + 992
    for (int t = bx; t < 2016; t += GB) {
        if (t < 1024) {
            int b = t & 63, r = t >> 6;
            int cog = r >> 1, tz = r & 1;
            convs2_body<16, 32, 4, 62, 64, 30, 30, 1024, 32, 1, 1, 2>(
                b, tz, smem, Bb, ew3t + cog * 4, eb3 + cog * 4, A + (size_t)cog * 4 * 1024);
        } else {
            int i = (t - 1024) * 256 + tid;
            zframeA_elem(i, A);
            __syncthreads();   // keep uniform with conv tasks' barriers? not needed; harmless skip
        }
    }
    gsync(cnt, gen);

    // P4: e4 (A -> Bb padded [64,32,32,32]) + zero Z frames in Bb.  1024 + 1984
    for (int t = bx; t < 3008; t += GB) {
        if (t < 1024) {
            int b = t & 63, r = t >> 6;
            int cog = r >> 1, rb = r & 1;
            conv3_body<32, 32, 4, 1024, 32, 1, 1, false>(b, cog, rb, smem, A, ew4t, eb4, Bb);
        } else {
            int i = (t - 1024) * 256 + tid;
            zframeZ_elem(i, Bb);
        }
    }
    gsync(cnt, gen);

    // P5: e5  Bb -> A (lat, padded [64,64,32,32])   tasks 1024
    for (int t = bx; t < 1024; t += GB) {
        int b = t & 63, cog = t >> 6;
        conv1_body<32, 64, 4>(b, cog, smem, Bb, ew5t, eb5, A);
    }
    gsync(cnt, gen);

    // P6: vq argmin    tasks 1800
    for (int t = bx; t < 1800; t += GB) {
        int q = t & 7, pb = t >> 3;
        vqargmin_body(pb, q, smem, A, cb, hcbn, keys);
    }
    gsync(cnt, gen);

    // P7: vq finalize (z -> Bb, loss)   tasks 225
    for (int t = bx; t < 225; t += GB)
        vqfin_body(t, smem, A, cb, keys, Bb, loss);
    gsync(cnt, gen);

    // P8: d1  Bb(z) -> A [64,32,30,(34)]   tasks 1024
    for (int t = bx; t < 1024; t += GB) {
        int b = t & 63, r = t >> 6;
        int cog = r >> 1, rb = r & 1;
        conv3_body<64, 32, 4, 30 * 34, 34, 1, 0, true>(b, cog, rb, smem, Bb, dw1t, db1, A);
    }
    gsync(cnt, gen);

    // P9: d2 (A -> Bb [64,16,63,(66)]) + zero Bb side cols.   2048 + 756
    for (int t = bx; t < 2804; t += GB) {
        if (t < 2048) {
            int b = t & 63, r = t >> 6;
            int cog = r >> 3, tz = r & 7;
            convt2_body<32, 16, 4, 30, 34, 63, 63, 63 * 66, 66, 1, 16, 1, 2, false>(
                b, cog, tz, smem, A, dw2t, db2, Bb);
        } else {
            int i = (t - 2048) * 256 + tid;
            zsB_elem(i, Bb);
        }
    }
    gsync(cnt, gen);

    // P10: d3 (Bb -> A [64,8,129,(132)]) + zero A side cols.   4608 + 774
    for (int t = bx; t < 5382; t += GB) {
        if (t < 4608) {
            int b = t & 63, tz = t >> 6;
            convt2_body<16, 8, 8, 63, 66, 129, 129, 129 * 132, 132, 1, 32, 2, 9, false>(
                b, 0, tz, smem, Bb, dw3t, db3, A);
        } else {
            int i = (t - 4608) * 256 + tid;
            zsA_elem(i, A);
        }
    }
    gsync(cnt, gen);

    // P11: d4 (A -> out [64,1,260,260], tanh) + loss_final.   13056 + 1
    for (int t = bx; t < 13057; t += GB) {
        if (t < 13056) {
            int b = t & 63, tz = t >> 6;
            convt2_body<8, 1, 1, 129, 132, 260, 260, 67600, 260, 0, 32, 3, 17, true>(
                b, 0, tz, smem, A, dw4t, db4, out);
        } else if (tid == 0) {
            out[out_size - 1] = 1.25f * loss[0] / (57600.f * 64.f);
        }
    }
}

extern "C" void kernel_launch(void* const* d_in, const int* in_sizes, int n_in,
                              void* d_out, int out_size, void* d_ws, size_t ws_size,
                              hipStream_t stream) {
    const float* x   = (const float*)d_in[0];
    const float* ew1 = (const float*)d_in[1];  const float* eb1 = (const float*)d_in[2];
    const float* ew2 = (const float*)d_in[3];  const float* eb2 = (const float*)d_in[4];
    const float* ew3 = (const float*)d_in[5];  const float* eb3 = (const float*)d_in[6];
    const float* ew4 = (const float*)d_in[7];  const float* eb4 = (const float*)d_in[8];
    const float* ew5 = (const float*)d_in[9];  const float* eb5 = (const float*)d_in[10];
    const float* dw1 = (const float*)d_in[11]; const float* db1 = (const float*)d_in[12];
    const float* dw2 = (const float*)d_in[13]; const float* db2 = (const float*)d_in[14];
    const float* dw3 = (const float*)d_in[15]; const float* db3 = (const float*)d_in[16];
    const float* dw4 = (const float*)d_in[17]; const float* db4 = (const float*)d_in[18];
    const float* cb  = (const float*)d_in[19];
    float* out = (float*)d_out;

    char* ws = (char*)d_ws;
    float* A    = (float*)(ws);
    float* Bb   = (float*)(ws + 34873344);
    unsigned long long* keys = (unsigned long long*)(ws + 51904512);
    float* hcbn = (float*)(ws + 52365312);
    float* loss = (float*)(ws + 52367360);
    unsigned* cnt = (unsigned*)(ws + 52367424);
    unsigned* gen = (unsigned*)(ws + 52367552);
    float* wtb  = (float*)(ws + 52367616);

    // barrier state must be zero every launch (ws is re-poisoned to 0xAA)
    hipMemsetAsync(ws + 52367424, 0, 256, stream);

    mega_k<<<GB, 256, 0, stream>>>(x, ew1, eb1, ew2, eb2, ew3, eb3, ew4, eb4,
                                   ew5, eb5, dw1, db1, dw2, db2, dw3, db3,
                                   dw4, db4, cb, out, out_size,
                                   A, Bb, keys, hcbn, loss, wtb, cnt, gen);
}

// Round 12
// 479.479 us; speedup vs baseline: 3.0281x; 3.0281x over previous
//
#include <hip/hip_runtime.h>
#include <hip/hip_bf16.h>
#include <math.h>

#define LRELU 0.01f

// ---------- vectorized LDS weight fetch ----------
template<int NW>
__device__ __forceinline__ void ldw(const float* p, float* w) {
    if constexpr (NW % 4 == 0) {
#pragma unroll
        for (int u = 0; u < NW / 4; u++) {
            float4 v = *(const float4*)(p + 4 * u);
            w[4*u] = v.x; w[4*u+1] = v.y; w[4*u+2] = v.z; w[4*u+3] = v.w;
        }
    } else {
#pragma unroll
        for (int c = 0; c < NW; c++) w[c] = p[c];
    }
}

// ======================= fused prep =======================
__device__ __forceinline__ void wfwd(const float* s, float* d, int CIN, int COUT,
                                     int KK, int i) {
    int co = i / (CIN * KK); int r = i - co * CIN * KK;
    int ci = r / KK; int t = r - ci * KK;
    d[(ci * KK + t) * COUT + co] = s[i];
}
__device__ __forceinline__ void wtr(const float* s, float* d, int CIN, int COUT,
                                    int KK, int i) {
    int ci = i / (COUT * KK); int r = i - ci * COUT * KK;
    int co = r / KK; int t = r - co * KK;
    d[(t * CIN + ci) * COUT + co] = s[i];
}
__global__ __launch_bounds__(256)
void prep_k(const float* e1, const float* e2, const float* e3, const float* e4,
            const float* e5, const float* d1, const float* d2, const float* d3,
            const float* d4, float* w, const float* cbp, float* hcbn,
            unsigned long long* keys, float* loss, int N) {
    int i = blockIdx.x * 256 + threadIdx.x;
    if      (i < 128)   wfwd(e1, w + 0,     1,  8, 16, i);
    else if (i < 2176)  wfwd(e2, w + 128,   8, 16, 16, i - 128);
    else if (i < 10368) wfwd(e3, w + 2176, 16, 32, 16, i - 2176);
    else if (i < 19584) wfwd(e4, w + 10368, 32, 32, 9, i - 10368);
    else if (i < 21632) wfwd(e5, w + 19584, 32, 64, 1, i - 19584);
    else if (i < 40064) wfwd(d1, w + 21632, 64, 32, 9, i - 21632);
    else if (i < 48256) wtr (d2, w + 40064, 32, 16, 16, i - 40064);
    else if (i < 50304) wtr (d3, w + 48256, 16,  8, 16, i - 48256);
    else if (i < 50432) wtr (d4, w + 50304,  8,  1, 16, i - 50304);
    else if (i < 50944) {
        int k = i - 50432;
        const float* c = cbp + k * 64;
        float s = 0.f;
#pragma unroll
        for (int d = 0; d < 64; d++) s = fmaf(c[d], c[d], s);
        hcbn[k] = 0.5f * s;
    } else if (i < 50944 + N) {
        keys[i - 50944] = 0xFFFFFFFFFFFFFFFFull;
    } else if (i == 50944 + N) {
        loss[0] = 0.f;
    }
}

// ======================= k4 s2 forward conv (+optional frame-zero slices) ===
// grid: (B, cog, ZCONV conv-slices [+ frame slices, y==0 only])
template<int CIN, int COUT, int CO_BLK, int HIN, int ISTR, int HOUT, int WOUT,
         int OPLANE, int OSTR, int OPAD, int CB, int RB, int ZCONV, int ZF_CH>
__global__ __launch_bounds__(256)
void convs2_k(const float* __restrict__ in, const float* __restrict__ wt,
              const float* __restrict__ bias, float* __restrict__ out) {
    const int b = blockIdx.x, cog = blockIdx.y, tid = threadIdx.x;
    if (ZF_CH > 0 && (int)blockIdx.z >= ZCONV) {
        if (cog != 0) return;
        int i = ((int)blockIdx.z - ZCONV) * 256 + tid;
        if (i >= ZF_CH * 124) return;
        int ch = i / 124, s = i - ch * 124;
        int r, c;
        if (s < 32)      { r = 0;  c = s; }
        else if (s < 64) { r = 31; c = s - 32; }
        else { int u = s - 64; r = 1 + (u >> 1); c = (u & 1) * 31; }
        out[(size_t)(b * ZF_CH + ch) * 1024 + r * 32 + c] = 0.f;
        return;
    }
    __shared__ __align__(16) float lw[CIN * 16 * CO_BLK];
    for (int i = tid; i < CIN * 16 * CO_BLK; i += 256) {
        int row = i / CO_BLK, c = i - row * CO_BLK;
        lw[i] = wt[row * COUT + cog * CO_BLK + c];
    }
    __syncthreads();

    const int tz = blockIdx.z;
    const int cbi = tz / RB, rb = tz - cbi * RB;
    const int tx = tid & 15, ty = tid >> 4;
    const int ow0 = (cbi * 16 + tx) * 2;
    const int oh  = rb * 16 + ty;
    if (oh >= HOUT || ow0 >= WOUT) return;
    const bool p1v = (ow0 + 1) < WOUT;

    float acc[CO_BLK][2];
#pragma unroll
    for (int c = 0; c < CO_BLK; c++) {
        float bv = bias[cog * CO_BLK + c];
        acc[c][0] = bv; acc[c][1] = bv;
    }
    const float* inb = in + ((size_t)(b * CIN) * HIN + oh * 2) * ISTR + ow0 * 2;
#pragma unroll 2
    for (int ci = 0; ci < CIN; ci++) {
        const float* r = inb + (size_t)ci * HIN * ISTR;
        float4 a4[4]; float2 b2[4];
#pragma unroll
        for (int kh = 0; kh < 4; kh++) {
            a4[kh] = *(const float4*)(r + kh * ISTR);
            b2[kh] = p1v ? *(const float2*)(r + kh * ISTR + 4) : make_float2(0.f, 0.f);
        }
        const float* wr = lw + ci * 16 * CO_BLK;
#pragma unroll
        for (int kh = 0; kh < 4; kh++) {
            float x0[4] = {a4[kh].x, a4[kh].y, a4[kh].z, a4[kh].w};
            float x1[4] = {a4[kh].z, a4[kh].w, b2[kh].x, b2[kh].y};
#pragma unroll
            for (int kw = 0; kw < 4; kw++) {
                float wv[CO_BLK];
                ldw<CO_BLK>(wr + (kh * 4 + kw) * CO_BLK, wv);
#pragma unroll
                for (int c = 0; c < CO_BLK; c++) {
                    acc[c][0] = fmaf(x0[kw], wv[c], acc[c][0]);
                    acc[c][1] = fmaf(x1[kw], wv[c], acc[c][1]);
                }
            }
        }
    }
    float* ob = out + (size_t)(b * COUT + cog * CO_BLK) * OPLANE
                    + (oh + OPAD) * OSTR + ow0 + OPAD;
#pragma unroll
    for (int c = 0; c < CO_BLK; c++) {
        float v0 = acc[c][0]; v0 = (v0 >= 0.f) ? v0 : LRELU * v0;
        ob[(size_t)c * OPLANE] = v0;
        if (p1v) {
            float v1 = acc[c][1]; v1 = (v1 >= 0.f) ? v1 : LRELU * v1;
            ob[(size_t)c * OPLANE + 1] = v1;
        }
    }
}

// ======================= k3 s1 p1 conv (+optional frame-zero slices) ========
template<int CIN, int COUT, int CO_BLK, int OPLANE, int OSTR, int OPADH, int OPADV,
         bool ZSIDE, int ZCONV, int ZF_CH>
__global__ __launch_bounds__(256)
void conv3_k(const float* __restrict__ in, const float* __restrict__ wt,
             const float* __restrict__ bias, float* __restrict__ out) {
    const int b = blockIdx.x, cog = blockIdx.y, tid = threadIdx.x;
    if (ZF_CH > 0 && (int)blockIdx.z >= ZCONV) {
        if (cog != 0) return;
        int i = ((int)blockIdx.z - ZCONV) * 256 + tid;
        if (i >= ZF_CH * 124) return;
        int ch = i / 124, s = i - ch * 124;
        int r, c;
        if (s < 32)      { r = 0;  c = s; }
        else if (s < 64) { r = 31; c = s - 32; }
        else { int u = s - 64; r = 1 + (u >> 1); c = (u & 1) * 31; }
        out[(size_t)(b * ZF_CH + ch) * 1024 + r * 32 + c] = 0.f;
        return;
    }
    __shared__ __align__(16) float lw[CIN * 9 * CO_BLK];
    for (int i = tid; i < CIN * 9 * CO_BLK; i += 256) {
        int row = i / CO_BLK, c = i - row * CO_BLK;
        lw[i] = wt[row * COUT + cog * CO_BLK + c];
    }
    __syncthreads();

    const int rb = blockIdx.z;
    const int tx = tid & 15, ty = tid >> 4;
    const int r = rb * 16 + ty;
    if (r >= 30) return;
    const int ow0 = tx * 2;
    if (tx == 15) {
        if (ZSIDE) {
#pragma unroll
            for (int c = 0; c < CO_BLK; c++) {
                float* base = out + (size_t)(b * COUT + cog * CO_BLK + c) * OPLANE
                                  + (r + OPADV) * OSTR;
                base[0] = 0.f; base[31] = 0.f; base[32] = 0.f;
            }
        }
        return;
    }
    float acc[CO_BLK][2];
#pragma unroll
    for (int c = 0; c < CO_BLK; c++) {
        float bv = bias[cog * CO_BLK + c];
        acc[c][0] = bv; acc[c][1] = bv;
    }
    const float* inb = in + ((size_t)(b * CIN) * 32 + r) * 32 + ow0;
#pragma unroll 2
    for (int ci = 0; ci < CIN; ci++) {
        const float* rr = inb + (size_t)ci * 1024;
        float2 A[3], Bv[3];
#pragma unroll
        for (int kh = 0; kh < 3; kh++) {
            A[kh]  = *(const float2*)(rr + kh * 32);
            Bv[kh] = *(const float2*)(rr + kh * 32 + 2);
        }
        const float* wr = lw + ci * 9 * CO_BLK;
#pragma unroll
        for (int kh = 0; kh < 3; kh++) {
            float x0[3] = {A[kh].x, A[kh].y, Bv[kh].x};
            float x1[3] = {A[kh].y, Bv[kh].x, Bv[kh].y};
#pragma unroll
            for (int kw = 0; kw < 3; kw++) {
                float wv[CO_BLK];
                ldw<CO_BLK>(wr + (kh * 3 + kw) * CO_BLK, wv);
#pragma unroll
                for (int c = 0; c < CO_BLK; c++) {
                    acc[c][0] = fmaf(x0[kw], wv[c], acc[c][0]);
                    acc[c][1] = fmaf(x1[kw], wv[c], acc[c][1]);
                }
            }
        }
    }
    float* ob = out + (size_t)(b * COUT + cog * CO_BLK) * OPLANE
                    + (r + OPADV) * OSTR + ow0 + OPADH;
#pragma unroll
    for (int c = 0; c < CO_BLK; c++) {
        float v0 = acc[c][0]; v0 = (v0 >= 0.f) ? v0 : LRELU * v0;
        float v1 = acc[c][1]; v1 = (v1 >= 0.f) ? v1 : LRELU * v1;
        ob[(size_t)c * OPLANE] = v0;
        ob[(size_t)c * OPLANE + 1] = v1;
    }
}

// ======================= 1x1 conv =======================
template<int CIN, int COUT, int CO_BLK>
__global__ __launch_bounds__(256)
void conv1_k(const float* __restrict__ in, const float* __restrict__ wt,
             const float* __restrict__ bias, float* __restrict__ out) {
    __shared__ __align__(16) float lw[CIN * CO_BLK];
    const int b = blockIdx.x, cog = blockIdx.y;
    for (int i = threadIdx.x; i < CIN * CO_BLK; i += 256) {
        int row = i / CO_BLK, c = i - row * CO_BLK;
        lw[i] = wt[row * COUT + cog * CO_BLK + c];
    }
    __syncthreads();

    const int px4 = threadIdx.x * 4;
    float acc[CO_BLK][4];
#pragma unroll
    for (int c = 0; c < CO_BLK; c++) {
        float bv = bias[cog * CO_BLK + c];
        acc[c][0] = bv; acc[c][1] = bv; acc[c][2] = bv; acc[c][3] = bv;
    }
#pragma unroll 4
    for (int ci = 0; ci < CIN; ci++) {
        float4 x = *(const float4*)(in + (size_t)(b * CIN + ci) * 1024 + px4);
        float wv[CO_BLK];
        ldw<CO_BLK>(lw + ci * CO_BLK, wv);
#pragma unroll
        for (int c = 0; c < CO_BLK; c++) {
            acc[c][0] = fmaf(x.x, wv[c], acc[c][0]);
            acc[c][1] = fmaf(x.y, wv[c], acc[c][1]);
            acc[c][2] = fmaf(x.z, wv[c], acc[c][2]);
            acc[c][3] = fmaf(x.w, wv[c], acc[c][3]);
        }
    }
#pragma unroll
    for (int c = 0; c < CO_BLK; c++) {
        float4 v;
        v.x = (acc[c][0] >= 0.f) ? acc[c][0] : LRELU * acc[c][0];
        v.y = (acc[c][1] >= 0.f) ? acc[c][1] : LRELU * acc[c][1];
        v.z = (acc[c][2] >= 0.f) ? acc[c][2] : LRELU * acc[c][2];
        v.w = (acc[c][3] >= 0.f) ? acc[c][3] : LRELU * acc[c][3];
        *(float4*)(out + (size_t)(b * COUT + cog * CO_BLK + c) * 1024 + px4) = v;
    }
}

// ======================= parity-fused convT k4 s2 ===========================
// thread = 2x2 output super-pixel (all 4 parities) x 2 col-supers x CO_BLK.
// weights LDS-packed [a*2+q][ci][py*2+px][co]; each b128 feeds 8 FMAs.
// grid: (B, 1, NCOG*NT conv slices [+ side-zero slices or loss slice])
template<int CIN, int COUT, int CO_BLK, int HIN, int ISTR, int HOUT, int WOUT,
         int OPLANE, int OSTR, int OPADH, int NTX, int NT,
         int ZS_CH, int ZS_H, int ZS_STR, int ZS_C0, bool DO_TANH, bool DO_LOSS>
__global__ __launch_bounds__(256)
void convtf_k(const float* __restrict__ in, const float* __restrict__ wt,
              const float* __restrict__ bias, float* __restrict__ out,
              const float* __restrict__ loss, float* __restrict__ losstgt) {
    const int b = blockIdx.x, tid = threadIdx.x;
    const int NCOG = COUT / CO_BLK;
    int zz = blockIdx.z;
    if (zz >= NCOG * NT) {
        if (DO_LOSS) {
            if (b == 0 && tid == 0)
                losstgt[0] = 1.25f * loss[0] / (57600.f * 64.f);
            return;
        }
        int i = (zz - NCOG * NT) * 256 + tid;
        if (i >= ZS_CH * ZS_H * 3) return;
        int ch = i / (ZS_H * 3); int u = i - ch * ZS_H * 3;
        int r = u / 3, c3 = u - r * 3;
        int col = (c3 == 0) ? 0 : (ZS_C0 + c3);
        out[((size_t)(b * ZS_CH + ch) * ZS_H + r) * ZS_STR + col] = 0.f;
        return;
    }
    const int cog = zz / NT, tile = zz - cog * NT;
    const int tlx = tile % NTX, tly = tile / NTX;

    __shared__ __align__(16) float lw[16 * CIN * CO_BLK];
    for (int i = tid; i < 16 * CIN * CO_BLK; i += 256) {
        int aq = i / (CIN * 4 * CO_BLK);
        int r1 = i - aq * (CIN * 4 * CO_BLK);
        int ci = r1 / (4 * CO_BLK);
        int u  = r1 - ci * (4 * CO_BLK);
        int pp = u / CO_BLK, c = u - pp * CO_BLK;
        int a = aq >> 1, q = aq & 1, py = pp >> 1, px = pp & 1;
        int tap = (py + 2 * a) * 4 + px + 2 * q;
        lw[i] = wt[((size_t)tap * CIN + ci) * COUT + cog * CO_BLK + c];
    }
    __syncthreads();

    const int SX = (WOUT + 1) >> 1, SY = (HOUT + 1) >> 1;
    const int sx0 = tlx * 32 + (tid & 15);
    const int sx1 = sx0 + 16;
    const int sy  = tly * 16 + (tid >> 4);
    const bool v0 = sx0 < SX, v1 = sx1 < SX;
    if (sy >= SY || !(v0 || v1)) return;

    const bool rvA = (sy < HIN);
    const bool rvB = (sy >= 1) && (sy <= HIN);

    float acc[2][4][CO_BLK];
#pragma unroll
    for (int s = 0; s < 2; s++)
#pragma unroll
        for (int o = 0; o < 4; o++)
#pragma unroll
            for (int c = 0; c < CO_BLK; c++)
                acc[s][o][c] = bias[cog * CO_BLK + c];

    const float* base = in + (size_t)(b * CIN) * HIN * ISTR;
#pragma unroll 2
    for (int ci = 0; ci < CIN; ci++) {
        const float* rowA = base + (size_t)ci * HIN * ISTR + (size_t)sy * ISTR;
        const float* rowB = rowA - ISTR;
        float rA0x = 0.f, rA0y = 0.f, rA1x = 0.f, rA1y = 0.f;
        float rB0x = 0.f, rB0y = 0.f, rB1x = 0.f, rB1y = 0.f;
        if (rvA) {
            if (v0) { rA0x = rowA[sx0]; rA0y = rowA[sx0 + 1]; }
            if (v1) { rA1x = rowA[sx1]; rA1y = rowA[sx1 + 1]; }
        }
        if (rvB) {
            if (v0) { rB0x = rowB[sx0]; rB0y = rowB[sx0 + 1]; }
            if (v1) { rB1x = rowB[sx1]; rB1y = rowB[sx1 + 1]; }
        }
#pragma unroll
        for (int a = 0; a < 2; a++) {
#pragma unroll
            for (int q = 0; q < 2; q++) {
                float iv0 = q ? (a ? rB0x : rA0x) : (a ? rB0y : rA0y);
                float iv1 = q ? (a ? rB1x : rA1x) : (a ? rB1y : rA1y);
                const float* wp = lw + (size_t)((a * 2 + q) * CIN + ci) * (4 * CO_BLK);
                float wv[4 * CO_BLK];
                ldw<4 * CO_BLK>(wp, wv);
#pragma unroll
                for (int o = 0; o < 4; o++)
#pragma unroll
                    for (int c = 0; c < CO_BLK; c++) {
                        acc[0][o][c] = fmaf(iv0, wv[o * CO_BLK + c], acc[0][o][c]);
                        acc[1][o][c] = fmaf(iv1, wv[o * CO_BLK + c], acc[1][o][c]);
                    }
            }
        }
    }
#pragma unroll
    for (int s = 0; s < 2; s++) {
        if (s ? !v1 : !v0) continue;
        const int sxx = s ? sx1 : sx0;
#pragma unroll
        for (int py = 0; py < 2; py++) {
            int oh = 2 * sy + py;
            if (oh >= HOUT) continue;
#pragma unroll
            for (int px = 0; px < 2; px++) {
                int ow = 2 * sxx + px;
                if (ow >= WOUT) continue;
                float* ob = out + (size_t)(b * COUT + cog * CO_BLK) * OPLANE
                                + (size_t)oh * OSTR + ow + OPADH;
#pragma unroll
                for (int c = 0; c < CO_BLK; c++) {
                    float v = acc[s][py * 2 + px][c];
                    if (DO_TANH) v = tanhf(v);
                    else v = (v >= 0.f) ? v : LRELU * v;
                    ob[(size_t)c * OPLANE] = v;
                }
            }
        }
    }
}

// ======================= VQ argmin (split via kofs) =========================
__global__ __launch_bounds__(256)
void vq_argmin_k(const float* __restrict__ lat, const float* __restrict__ cb,
                 const float* __restrict__ hcbn,
                 unsigned long long* __restrict__ keys, int kofs) {
    const int pb = blockIdx.x;
    if (pb >= 225) return;
    __shared__ float4 scb4[1024];
    __shared__ float  shn[64];
    const int tid = threadIdx.x;
    const int dq  = tid & 3;
    const int pg  = tid >> 2;
    const int kbase = (blockIdx.y + kofs) * 64;
    const int posbase = pb * 256;

    const float4* src = (const float4*)(cb + (size_t)kbase * 64);
#pragma unroll
    for (int i = 0; i < 4; i++) scb4[tid + 256 * i] = src[tid + 256 * i];
    if (tid < 64) shn[tid] = hcbn[kbase + tid];

    float l[4][16];
    int   pidx[4];
#pragma unroll
    for (int j = 0; j < 4; j++) {
        int pos = posbase + pg + 64 * j;
        pidx[j] = pos;
        int b = pos / 900, p = pos - b * 900;
        int oh = p / 30, ow = p - oh * 30;
        int pp = 33 + oh * 32 + ow;
        const float* lb = lat + ((size_t)b * 64 + dq * 16) * 1024 + pp;
#pragma unroll
        for (int i = 0; i < 16; i++) l[j][i] = lb[i * 1024];
    }
    __syncthreads();

    float best[4] = {3.4e38f, 3.4e38f, 3.4e38f, 3.4e38f};
    int   bi[4]   = {0, 0, 0, 0};
#pragma unroll 2
    for (int k0 = 0; k0 < 64; k0++) {
        float4 c0 = scb4[k0 * 16 + dq * 4 + 0];
        float4 c1 = scb4[k0 * 16 + dq * 4 + 1];
        float4 c2 = scb4[k0 * 16 + dq * 4 + 2];
        float4 c3 = scb4[k0 * 16 + dq * 4 + 3];
        float hn = shn[k0];
#pragma unroll
        for (int j = 0; j < 4; j++) {
            float dot = 0.f;
            dot = fmaf(l[j][0],  c0.x, dot); dot = fmaf(l[j][1],  c0.y, dot);
            dot = fmaf(l[j][2],  c0.z, dot); dot = fmaf(l[j][3],  c0.w, dot);
            dot = fmaf(l[j][4],  c1.x, dot); dot = fmaf(l[j][5],  c1.y, dot);
            dot = fmaf(l[j][6],  c1.z, dot); dot = fmaf(l[j][7],  c1.w, dot);
            dot = fmaf(l[j][8],  c2.x, dot); dot = fmaf(l[j][9],  c2.y, dot);
            dot = fmaf(l[j][10], c2.z, dot); dot = fmaf(l[j][11], c2.w, dot);
            dot = fmaf(l[j][12], c3.x, dot); dot = fmaf(l[j][13], c3.y, dot);
            dot = fmaf(l[j][14], c3.z, dot); dot = fmaf(l[j][15], c3.w, dot);
            float full = dot + __shfl_xor(dot, 1);
            full += __shfl_xor(full, 2);
            float score = hn - full;
            if (score < best[j]) { best[j] = score; bi[j] = kbase + k0; }
        }
    }
    if (dq == 0) {
#pragma unroll
        for (int j = 0; j < 4; j++) {
            unsigned u = __float_as_uint(best[j]);
            u = ((int)u < 0) ? ~u : (u | 0x80000000u);
            unsigned long long key = ((unsigned long long)u << 32) | (unsigned)bi[j];
            atomicMin(&keys[pidx[j]], key);
        }
    }
}

// ======================= VQ finalize =======================
__global__ __launch_bounds__(256)
void vq_finalize_k(const float* __restrict__ lat, const float* __restrict__ cb,
                   const unsigned long long* __restrict__ keys,
                   float* __restrict__ z, float* __restrict__ loss_acc, int B) {
    int gid = blockIdx.x * 256 + threadIdx.x;
    const int N = B * 900;
    float myloss = 0.f;
    if (gid < N) {
        int b = gid / 900, p = gid - b * 900;
        int oh = p / 30, ow = p - oh * 30;
        int pp = 33 + oh * 32 + ow;
        int idx = (int)(unsigned)(keys[gid] & 0xFFFFFFFFull);
        const float4* crow = (const float4*)(cb + (size_t)idx * 64);
        const float* lrow = lat + (size_t)b * 64 * 1024 + pp;
        float*       zrow = z   + (size_t)b * 64 * 1024 + pp;
#pragma unroll
        for (int i = 0; i < 16; i++) {
            float4 cv = crow[i];
            float lv0 = lrow[(4 * i + 0) * 1024];
            float lv1 = lrow[(4 * i + 1) * 1024];
            float lv2 = lrow[(4 * i + 2) * 1024];
            float lv3 = lrow[(4 * i + 3) * 1024];
            zrow[(4 * i + 0) * 1024] = cv.x;
            zrow[(4 * i + 1) * 1024] = cv.y;
            zrow[(4 * i + 2) * 1024] = cv.z;
            zrow[(4 * i + 3) * 1024] = cv.w;
            float d0 = cv.x - lv0, d1 = cv.y - lv1, d2 = cv.z - lv2, d3 = cv.w - lv3;
            myloss = fmaf(d0, d0, myloss);
            myloss = fmaf(d1, d1, myloss);
            myloss = fmaf(d2, d2, myloss);
            myloss = fmaf(d3, d3, myloss);
        }
    }
    __shared__ float red[256];
    red[threadIdx.x] = myloss;
    __syncthreads();
    for (int s = 128; s > 0; s >>= 1) {
        if ((int)threadIdx.x < s) red[threadIdx.x] += red[threadIdx.x + s];
        __syncthreads();
    }
    if (threadIdx.x == 0) atomicAdd(loss_acc, red[0]);
}

static inline int nblk(long long total) { return (int)((total + 255) / 256); }

extern "C" void kernel_launch(void* const* d_in, const int* in_sizes, int n_in,
                              void* d_out, int out_size, void* d_ws, size_t ws_size,
                              hipStream_t stream) {
    const float* x   = (const float*)d_in[0];
    const float* ew1 = (const float*)d_in[1];  const float* eb1 = (const float*)d_in[2];
    const float* ew2 = (const float*)d_in[3];  const float* eb2 = (const float*)d_in[4];
    const float* ew3 = (const float*)d_in[5];  const float* eb3 = (const float*)d_in[6];
    const float* ew4 = (const float*)d_in[7];  const float* eb4 = (const float*)d_in[8];
    const float* ew5 = (const float*)d_in[9];  const float* eb5 = (const float*)d_in[10];
    const float* dw1 = (const float*)d_in[11]; const float* db1 = (const float*)d_in[12];
    const float* dw2 = (const float*)d_in[13]; const float* db2 = (const float*)d_in[14];
    const float* dw3 = (const float*)d_in[15]; const float* db3 = (const float*)d_in[16];
    const float* dw4 = (const float*)d_in[17]; const float* db4 = (const float*)d_in[18];
    const float* cb  = (const float*)d_in[19];
    float* out = (float*)d_out;

    const int B = in_sizes[0] / (256 * 256);   // 64
    const int N = B * 900;                     // 57600

    char* ws = (char*)d_ws;
    float* A  = (float*)(ws);
    float* Bb = (float*)(ws + 34873344);
    unsigned long long* keys = (unsigned long long*)(ws + 51904512);
    float* hcbn = (float*)(ws + 52365312);
    float* loss = (float*)(ws + 52367360);
    float* wtb  = (float*)(ws + 52367616);
    float* ew1t = wtb;          float* ew2t = wtb + 128;
    float* ew3t = wtb + 2176;   float* ew4t = wtb + 10368;
    float* ew5t = wtb + 19584;  float* dw1t = wtb + 21632;
    float* dw2t = wtb + 40064;  float* dw3t = wtb + 48256;
    float* dw4t = wtb + 50304;

    prep_k<<<nblk(50945 + N), 256, 0, stream>>>(ew1, ew2, ew3, ew4, ew5,
                                                dw1, dw2, dw3, dw4, wtb,
                                                cb, hcbn, keys, loss, N);

    // ---- encoder ----
    convs2_k<1, 8, 8, 256, 256, 127, 127, 127 * 128, 128, 0, 4, 8, 32, 0>
        <<<dim3(B, 1, 32), 256, 0, stream>>>(x, ew1t, eb1, A);
    convs2_k<8, 16, 4, 127, 128, 62, 62, 62 * 64, 64, 0, 2, 4, 8, 0>
        <<<dim3(B, 4, 8), 256, 0, stream>>>(A, ew2t, eb2, Bb);
    // e3 + A-frame zeroing (16 slices: 32*124=3968 elems/image)
    convs2_k<16, 32, 4, 62, 64, 30, 30, 1024, 32, 1, 1, 2, 2, 32>
        <<<dim3(B, 8, 18), 256, 0, stream>>>(Bb, ew3t, eb3, A);
    // e4 + z-frame zeroing in Bb (31 slices: 64*124=7936 elems/image)
    conv3_k<32, 32, 4, 1024, 32, 1, 1, false, 2, 64>
        <<<dim3(B, 8, 33), 256, 0, stream>>>(A, ew4t, eb4, Bb);
    conv1_k<32, 64, 4><<<dim3(B, 16, 1), 256, 0, stream>>>(Bb, ew5t, eb5, A);

    // ---- VQ (argmin split in two for profiling visibility) ----
    vq_argmin_k<<<dim3(232, 4), 256, 0, stream>>>(A, cb, hcbn, keys, 0);
    vq_argmin_k<<<dim3(232, 4), 256, 0, stream>>>(A, cb, hcbn, keys, 4);
    vq_finalize_k<<<nblk(N), 256, 0, stream>>>(A, cb, keys, Bb, loss, B);

    // ---- decoder ----
    conv3_k<64, 32, 4, 30 * 34, 34, 1, 0, true, 2, 0>
        <<<dim3(B, 8, 2), 256, 0, stream>>>(Bb, dw1t, db1, A);
    // d2: A -> Bb [64,16,63,(66)], + side-col zeroing of d2out (12 slices)
    convtf_k<32, 16, 4, 30, 34, 63, 63, 63 * 66, 66, 1, 1, 2,
             16, 63, 66, 63, false, false>
        <<<dim3(B, 1, 20), 256, 0, stream>>>(A, dw2t, db2, Bb, nullptr, nullptr);
    // d3: Bb -> A [64,8,129,(132)], + side-col zeroing of d3out (13 slices)
    convtf_k<16, 8, 8, 63, 66, 129, 129, 129 * 132, 132, 1, 3, 15,
             8, 129, 132, 129, false, false>
        <<<dim3(B, 1, 28), 256, 0, stream>>>(Bb, dw3t, db3, A, nullptr, nullptr);
    // d4: A -> out [64,1,260,260], tanh, + loss-final slice
    convtf_k<8, 1, 1, 129, 132, 260, 260, 67600, 260, 0, 5, 45,
             0, 1, 1, 0, true, true>
        <<<dim3(B, 1, 46), 256, 0, stream>>>(A, dw4t, db4, out, loss,
                                             out + (out_size - 1));
}

// Round 13
// 420.065 us; speedup vs baseline: 3.4564x; 1.1414x over previous
//
#include <hip/hip_runtime.h>
#include <hip/hip_bf16.h>
#include <math.h>

#define LRELU 0.01f

// ---------- vectorized LDS weight fetch ----------
template<int NW>
__device__ __forceinline__ void ldw(const float* p, float* w) {
    if constexpr (NW % 4 == 0) {
#pragma unroll
        for (int u = 0; u < NW / 4; u++) {
            float4 v = *(const float4*)(p + 4 * u);
            w[4*u] = v.x; w[4*u+1] = v.y; w[4*u+2] = v.z; w[4*u+3] = v.w;
        }
    } else {
#pragma unroll
        for (int c = 0; c < NW; c++) w[c] = p[c];
    }
}

// ======================= fused prep =======================
__device__ __forceinline__ void wfwd(const float* s, float* d, int CIN, int COUT,
                                     int KK, int i) {
    int co = i / (CIN * KK); int r = i - co * CIN * KK;
    int ci = r / KK; int t = r - ci * KK;
    d[(ci * KK + t) * COUT + co] = s[i];
}
__device__ __forceinline__ void wtr(const float* s, float* d, int CIN, int COUT,
                                    int KK, int i) {
    int ci = i / (COUT * KK); int r = i - ci * COUT * KK;
    int co = r / KK; int t = r - co * KK;
    d[(t * CIN + ci) * COUT + co] = s[i];
}
__global__ __launch_bounds__(256)
void prep_k(const float* e1, const float* e2, const float* e3, const float* e4,
            const float* e5, const float* d1, const float* d2, const float* d3,
            const float* d4, float* w, const float* cbp, float* hcbn,
            unsigned long long* keys, float* loss, int* idxm, int N) {
    int i = blockIdx.x * 256 + threadIdx.x;
    if      (i < 128)   wfwd(e1, w + 0,     1,  8, 16, i);
    else if (i < 2176)  wfwd(e2, w + 128,   8, 16, 16, i - 128);
    else if (i < 10368) wfwd(e3, w + 2176, 16, 32, 16, i - 2176);
    else if (i < 19584) wfwd(e4, w + 10368, 32, 32, 9, i - 10368);
    else if (i < 21632) wfwd(e5, w + 19584, 32, 64, 1, i - 19584);
    else if (i < 40064) wfwd(d1, w + 21632, 64, 32, 9, i - 21632);
    else if (i < 48256) wtr (d2, w + 40064, 32, 16, 16, i - 40064);
    else if (i < 50304) wtr (d3, w + 48256, 16,  8, 16, i - 48256);
    else if (i < 50432) wtr (d4, w + 50304,  8,  1, 16, i - 50304);
    else if (i < 50944) {
        int k = i - 50432;
        const float* c = cbp + k * 64;
        float s = 0.f;
#pragma unroll
        for (int d = 0; d < 64; d++) s = fmaf(c[d], c[d], s);
        hcbn[k] = 0.5f * s;
    } else if (i < 50944 + N) {
        keys[i - 50944] = 0xFFFFFFFFFFFFFFFFull;
    } else if (i == 50944 + N) {
        loss[0] = 0.f;
    } else if (i < 50945 + N + 64 * 124) {
        // idx-map padding frame = sentinel 512 (U[512] == 0)
        int j = i - (50945 + N);
        int b2 = j / 124, s = j - b2 * 124;
        int r, c;
        if (s < 32)      { r = 0;  c = s; }
        else if (s < 64) { r = 31; c = s - 32; }
        else { int u = s - 64; r = 1 + (u >> 1); c = (u & 1) * 31; }
        idxm[b2 * 1024 + r * 32 + c] = 512;
    }
}

// ======================= U table: U[k][tap][co] = sum_ci w[ci][tap][co]*cb[k][ci]
__global__ __launch_bounds__(256)
void ubuild_k(const float* __restrict__ w, const float* __restrict__ cb,
              float* __restrict__ U) {
    int g = blockIdx.x * 256 + threadIdx.x;
    if (g >= 513 * 288) return;
    if (g >= 512 * 288) { U[g] = 0.f; return; }
    int k = g / 288, rem = g - k * 288;     // rem = tap*32 + co
    const float* cr = cb + k * 64;
    float s = 0.f;
#pragma unroll 4
    for (int ci = 0; ci < 64; ci++)
        s = fmaf(w[ci * 288 + rem], cr[ci], s);
    U[g] = s;
}

// ======================= k4 s2 forward conv (+optional frame-zero slices) ===
template<int CIN, int COUT, int CO_BLK, int HIN, int ISTR, int HOUT, int WOUT,
         int OPLANE, int OSTR, int OPAD, int CB, int RB, int ZCONV, int ZF_CH>
__global__ __launch_bounds__(256)
void convs2_k(const float* __restrict__ in, const float* __restrict__ wt,
              const float* __restrict__ bias, float* __restrict__ out) {
    const int b = blockIdx.x, cog = blockIdx.y, tid = threadIdx.x;
    if (ZF_CH > 0 && (int)blockIdx.z >= ZCONV) {
        if (cog != 0) return;
        int i = ((int)blockIdx.z - ZCONV) * 256 + tid;
        if (i >= ZF_CH * 124) return;
        int ch = i / 124, s = i - ch * 124;
        int r, c;
        if (s < 32)      { r = 0;  c = s; }
        else if (s < 64) { r = 31; c = s - 32; }
        else { int u = s - 64; r = 1 + (u >> 1); c = (u & 1) * 31; }
        out[(size_t)(b * ZF_CH + ch) * 1024 + r * 32 + c] = 0.f;
        return;
    }
    __shared__ __align__(16) float lw[CIN * 16 * CO_BLK];
    for (int i = tid; i < CIN * 16 * CO_BLK; i += 256) {
        int row = i / CO_BLK, c = i - row * CO_BLK;
        lw[i] = wt[row * COUT + cog * CO_BLK + c];
    }
    __syncthreads();

    const int tz = blockIdx.z;
    const int cbi = tz / RB, rb = tz - cbi * RB;
    const int tx = tid & 15, ty = tid >> 4;
    const int ow0 = (cbi * 16 + tx) * 2;
    const int oh  = rb * 16 + ty;
    if (oh >= HOUT || ow0 >= WOUT) return;
    const bool p1v = (ow0 + 1) < WOUT;

    float acc[CO_BLK][2];
#pragma unroll
    for (int c = 0; c < CO_BLK; c++) {
        float bv = bias[cog * CO_BLK + c];
        acc[c][0] = bv; acc[c][1] = bv;
    }
    const float* inb = in + ((size_t)(b * CIN) * HIN + oh * 2) * ISTR + ow0 * 2;
#pragma unroll 2
    for (int ci = 0; ci < CIN; ci++) {
        const float* r = inb + (size_t)ci * HIN * ISTR;
        float4 a4[4]; float2 b2[4];
#pragma unroll
        for (int kh = 0; kh < 4; kh++) {
            a4[kh] = *(const float4*)(r + kh * ISTR);
            b2[kh] = p1v ? *(const float2*)(r + kh * ISTR + 4) : make_float2(0.f, 0.f);
        }
        const float* wr = lw + ci * 16 * CO_BLK;
#pragma unroll
        for (int kh = 0; kh < 4; kh++) {
            float x0[4] = {a4[kh].x, a4[kh].y, a4[kh].z, a4[kh].w};
            float x1[4] = {a4[kh].z, a4[kh].w, b2[kh].x, b2[kh].y};
#pragma unroll
            for (int kw = 0; kw < 4; kw++) {
                float wv[CO_BLK];
                ldw<CO_BLK>(wr + (kh * 4 + kw) * CO_BLK, wv);
#pragma unroll
                for (int c = 0; c < CO_BLK; c++) {
                    acc[c][0] = fmaf(x0[kw], wv[c], acc[c][0]);
                    acc[c][1] = fmaf(x1[kw], wv[c], acc[c][1]);
                }
            }
        }
    }
    float* ob = out + (size_t)(b * COUT + cog * CO_BLK) * OPLANE
                    + (oh + OPAD) * OSTR + ow0 + OPAD;
#pragma unroll
    for (int c = 0; c < CO_BLK; c++) {
        float v0 = acc[c][0]; v0 = (v0 >= 0.f) ? v0 : LRELU * v0;
        ob[(size_t)c * OPLANE] = v0;
        if (p1v) {
            float v1 = acc[c][1]; v1 = (v1 >= 0.f) ? v1 : LRELU * v1;
            ob[(size_t)c * OPLANE + 1] = v1;
        }
    }
}

// ======================= k3 s1 p1 conv =======================
template<int CIN, int COUT, int CO_BLK, int OPLANE, int OSTR, int OPADH, int OPADV,
         bool ZSIDE>
__global__ __launch_bounds__(256)
void conv3_k(const float* __restrict__ in, const float* __restrict__ wt,
             const float* __restrict__ bias, float* __restrict__ out) {
    const int b = blockIdx.x, cog = blockIdx.y, tid = threadIdx.x;
    __shared__ __align__(16) float lw[CIN * 9 * CO_BLK];
    for (int i = tid; i < CIN * 9 * CO_BLK; i += 256) {
        int row = i / CO_BLK, c = i - row * CO_BLK;
        lw[i] = wt[row * COUT + cog * CO_BLK + c];
    }
    __syncthreads();

    const int rb = blockIdx.z;
    const int tx = tid & 15, ty = tid >> 4;
    const int r = rb * 16 + ty;
    if (r >= 30) return;
    const int ow0 = tx * 2;
    if (tx == 15) {
        if (ZSIDE) {
#pragma unroll
            for (int c = 0; c < CO_BLK; c++) {
                float* base = out + (size_t)(b * COUT + cog * CO_BLK + c) * OPLANE
                                  + (r + OPADV) * OSTR;
                base[0] = 0.f; base[31] = 0.f; base[32] = 0.f;
            }
        }
        return;
    }
    float acc[CO_BLK][2];
#pragma unroll
    for (int c = 0; c < CO_BLK; c++) {
        float bv = bias[cog * CO_BLK + c];
        acc[c][0] = bv; acc[c][1] = bv;
    }
    const float* inb = in + ((size_t)(b * CIN) * 32 + r) * 32 + ow0;
#pragma unroll 2
    for (int ci = 0; ci < CIN; ci++) {
        const float* rr = inb + (size_t)ci * 1024;
        float2 A[3], Bv[3];
#pragma unroll
        for (int kh = 0; kh < 3; kh++) {
            A[kh]  = *(const float2*)(rr + kh * 32);
            Bv[kh] = *(const float2*)(rr + kh * 32 + 2);
        }
        const float* wr = lw + ci * 9 * CO_BLK;
#pragma unroll
        for (int kh = 0; kh < 3; kh++) {
            float x0[3] = {A[kh].x, A[kh].y, Bv[kh].x};
            float x1[3] = {A[kh].y, Bv[kh].x, Bv[kh].y};
#pragma unroll
            for (int kw = 0; kw < 3; kw++) {
                float wv[CO_BLK];
                ldw<CO_BLK>(wr + (kh * 3 + kw) * CO_BLK, wv);
#pragma unroll
                for (int c = 0; c < CO_BLK; c++) {
                    acc[c][0] = fmaf(x0[kw], wv[c], acc[c][0]);
                    acc[c][1] = fmaf(x1[kw], wv[c], acc[c][1]);
                }
            }
        }
    }
    float* ob = out + (size_t)(b * COUT + cog * CO_BLK) * OPLANE
                    + (r + OPADV) * OSTR + ow0 + OPADH;
#pragma unroll
    for (int c = 0; c < CO_BLK; c++) {
        float v0 = acc[c][0]; v0 = (v0 >= 0.f) ? v0 : LRELU * v0;
        float v1 = acc[c][1]; v1 = (v1 >= 0.f) ? v1 : LRELU * v1;
        ob[(size_t)c * OPLANE] = v0;
        ob[(size_t)c * OPLANE + 1] = v1;
    }
}

// ======================= 1x1 conv =======================
template<int CIN, int COUT, int CO_BLK>
__global__ __launch_bounds__(256)
void conv1_k(const float* __restrict__ in, const float* __restrict__ wt,
             const float* __restrict__ bias, float* __restrict__ out) {
    __shared__ __align__(16) float lw[CIN * CO_BLK];
    const int b = blockIdx.x, cog = blockIdx.y;
    for (int i = threadIdx.x; i < CIN * CO_BLK; i += 256) {
        int row = i / CO_BLK, c = i - row * CO_BLK;
        lw[i] = wt[row * COUT + cog * CO_BLK + c];
    }
    __syncthreads();

    const int px4 = threadIdx.x * 4;
    float acc[CO_BLK][4];
#pragma unroll
    for (int c = 0; c < CO_BLK; c++) {
        float bv = bias[cog * CO_BLK + c];
        acc[c][0] = bv; acc[c][1] = bv; acc[c][2] = bv; acc[c][3] = bv;
    }
#pragma unroll 4
    for (int ci = 0; ci < CIN; ci++) {
        float4 x = *(const float4*)(in + (size_t)(b * CIN + ci) * 1024 + px4);
        float wv[CO_BLK];
        ldw<CO_BLK>(lw + ci * CO_BLK, wv);
#pragma unroll
        for (int c = 0; c < CO_BLK; c++) {
            acc[c][0] = fmaf(x.x, wv[c], acc[c][0]);
            acc[c][1] = fmaf(x.y, wv[c], acc[c][1]);
            acc[c][2] = fmaf(x.z, wv[c], acc[c][2]);
            acc[c][3] = fmaf(x.w, wv[c], acc[c][3]);
        }
    }
#pragma unroll
    for (int c = 0; c < CO_BLK; c++) {
        float4 v;
        v.x = (acc[c][0] >= 0.f) ? acc[c][0] : LRELU * acc[c][0];
        v.y = (acc[c][1] >= 0.f) ? acc[c][1] : LRELU * acc[c][1];
        v.z = (acc[c][2] >= 0.f) ? acc[c][2] : LRELU * acc[c][2];
        v.w = (acc[c][3] >= 0.f) ? acc[c][3] : LRELU * acc[c][3];
        *(float4*)(out + (size_t)(b * COUT + cog * CO_BLK + c) * 1024 + px4) = v;
    }
}

// ======================= d1 via code table =======================
// out[co,p] = bias + sum_tap U[idx(p+tap)][tap][co]; sentinel idx 512 -> 0.
// grid (64, 2 cog16, 4 row-tiles); thread = 1 px (8 rows x 32 cols).
__global__ __launch_bounds__(256)
void d1tab_k(const int* __restrict__ idxm, const float* __restrict__ U,
             const float* __restrict__ bias, float* __restrict__ out) {
    const int b = blockIdx.x, cog = blockIdx.y, rt = blockIdx.z;
    const int tx = threadIdx.x & 31, ty = threadIdx.x >> 5;
    const int r = rt * 8 + ty;
    if (r >= 30) return;
    if (tx >= 30) {
        if (tx == 31) {   // zero pad cols 0,31,32 of this row (16 ch)
#pragma unroll
            for (int c = 0; c < 16; c++) {
                float* base = out + (size_t)(b * 32 + cog * 16 + c) * 1020 + r * 34;
                base[0] = 0.f; base[31] = 0.f; base[32] = 0.f;
            }
        }
        return;
    }
    const int* im = idxm + b * 1024 + r * 32 + tx;   // neighbors (r+kh, tx+kw)
    float acc[16];
#pragma unroll
    for (int c = 0; c < 16; c++) acc[c] = bias[cog * 16 + c];
#pragma unroll
    for (int kh = 0; kh < 3; kh++) {
        int i0 = im[kh * 32 + 0];
        int i1 = im[kh * 32 + 1];
        int i2 = im[kh * 32 + 2];
        const float4* u0 = (const float4*)(U + ((size_t)i0 * 9 + kh * 3 + 0) * 32 + cog * 16);
        const float4* u1 = (const float4*)(U + ((size_t)i1 * 9 + kh * 3 + 1) * 32 + cog * 16);
        const float4* u2 = (const float4*)(U + ((size_t)i2 * 9 + kh * 3 + 2) * 32 + cog * 16);
#pragma unroll
        for (int q = 0; q < 4; q++) {
            float4 a = u0[q], bb = u1[q], cc = u2[q];
            acc[4*q+0] += (a.x + bb.x) + cc.x;
            acc[4*q+1] += (a.y + bb.y) + cc.y;
            acc[4*q+2] += (a.z + bb.z) + cc.z;
            acc[4*q+3] += (a.w + bb.w) + cc.w;
        }
    }
    float* ob = out + (size_t)(b * 32 + cog * 16) * 1020 + r * 34 + tx + 1;
#pragma unroll
    for (int c = 0; c < 16; c++) {
        float v = acc[c]; v = (v >= 0.f) ? v : LRELU * v;
        ob[(size_t)c * 1020] = v;
    }
}

// ======================= parity-fused convT k4 s2 ===========================
template<int CIN, int COUT, int CO_BLK, int HIN, int ISTR, int HOUT, int WOUT,
         int OPLANE, int OSTR, int OPADH, int NTX, int NT,
         int ZS_CH, int ZS_H, int ZS_STR, int ZS_C0, bool DO_TANH, bool DO_LOSS>
__global__ __launch_bounds__(256)
void convtf_k(const float* __restrict__ in, const float* __restrict__ wt,
              const float* __restrict__ bias, float* __restrict__ out,
              const float* __restrict__ loss, float* __restrict__ losstgt) {
    const int b = blockIdx.x, tid = threadIdx.x;
    const int NCOG = COUT / CO_BLK;
    int zz = blockIdx.z;
    if (zz >= NCOG * NT) {
        if (DO_LOSS) {
            if (b == 0 && tid == 0)
                losstgt[0] = 1.25f * loss[0] / (57600.f * 64.f);
            return;
        }
        int i = (zz - NCOG * NT) * 256 + tid;
        if (i >= ZS_CH * ZS_H * 3) return;
        int ch = i / (ZS_H * 3); int u = i - ch * ZS_H * 3;
        int r = u / 3, c3 = u - r * 3;
        int col = (c3 == 0) ? 0 : (ZS_C0 + c3);
        out[((size_t)(b * ZS_CH + ch) * ZS_H + r) * ZS_STR + col] = 0.f;
        return;
    }
    const int cog = zz / NT, tile = zz - cog * NT;
    const int tlx = tile % NTX, tly = tile / NTX;

    __shared__ __align__(16) float lw[16 * CIN * CO_BLK];
    for (int i = tid; i < 16 * CIN * CO_BLK; i += 256) {
        int aq = i / (CIN * 4 * CO_BLK);
        int r1 = i - aq * (CIN * 4 * CO_BLK);
        int ci = r1 / (4 * CO_BLK);
        int u  = r1 - ci * (4 * CO_BLK);
        int pp = u / CO_BLK, c = u - pp * CO_BLK;
        int a = aq >> 1, q = aq & 1, py = pp >> 1, px = pp & 1;
        int tap = (py + 2 * a) * 4 + px + 2 * q;
        lw[i] = wt[((size_t)tap * CIN + ci) * COUT + cog * CO_BLK + c];
    }
    __syncthreads();

    const int SX = (WOUT + 1) >> 1, SY = (HOUT + 1) >> 1;
    const int sx0 = tlx * 32 + (tid & 15);
    const int sx1 = sx0 + 16;
    const int sy  = tly * 16 + (tid >> 4);
    const bool v0 = sx0 < SX, v1 = sx1 < SX;
    if (sy >= SY || !(v0 || v1)) return;

    const bool rvA = (sy < HIN);
    const bool rvB = (sy >= 1) && (sy <= HIN);

    float acc[2][4][CO_BLK];
#pragma unroll
    for (int s = 0; s < 2; s++)
#pragma unroll
        for (int o = 0; o < 4; o++)
#pragma unroll
            for (int c = 0; c < CO_BLK; c++)
                acc[s][o][c] = bias[cog * CO_BLK + c];

    const float* base = in + (size_t)(b * CIN) * HIN * ISTR;
#pragma unroll 2
    for (int ci = 0; ci < CIN; ci++) {
        const float* rowA = base + (size_t)ci * HIN * ISTR + (size_t)sy * ISTR;
        const float* rowB = rowA - ISTR;
        float rA0x = 0.f, rA0y = 0.f, rA1x = 0.f, rA1y = 0.f;
        float rB0x = 0.f, rB0y = 0.f, rB1x = 0.f, rB1y = 0.f;
        if (rvA) {
            if (v0) { rA0x = rowA[sx0]; rA0y = rowA[sx0 + 1]; }
            if (v1) { rA1x = rowA[sx1]; rA1y = rowA[sx1 + 1]; }
        }
        if (rvB) {
            if (v0) { rB0x = rowB[sx0]; rB0y = rowB[sx0 + 1]; }
            if (v1) { rB1x = rowB[sx1]; rB1y = rowB[sx1 + 1]; }
        }
#pragma unroll
        for (int a = 0; a < 2; a++) {
#pragma unroll
            for (int q = 0; q < 2; q++) {
                float iv0 = q ? (a ? rB0x : rA0x) : (a ? rB0y : rA0y);
                float iv1 = q ? (a ? rB1x : rA1x) : (a ? rB1y : rA1y);
                const float* wp = lw + (size_t)((a * 2 + q) * CIN + ci) * (4 * CO_BLK);
                float wv[4 * CO_BLK];
                ldw<4 * CO_BLK>(wp, wv);
#pragma unroll
                for (int o = 0; o < 4; o++)
#pragma unroll
                    for (int c = 0; c < CO_BLK; c++) {
                        acc[0][o][c] = fmaf(iv0, wv[o * CO_BLK + c], acc[0][o][c]);
                        acc[1][o][c] = fmaf(iv1, wv[o * CO_BLK + c], acc[1][o][c]);
                    }
            }
        }
    }
#pragma unroll
    for (int s = 0; s < 2; s++) {
        if (s ? !v1 : !v0) continue;
        const int sxx = s ? sx1 : sx0;
#pragma unroll
        for (int py = 0; py < 2; py++) {
            int oh = 2 * sy + py;
            if (oh >= HOUT) continue;
#pragma unroll
            for (int px = 0; px < 2; px++) {
                int ow = 2 * sxx + px;
                if (ow >= WOUT) continue;
                float* ob = out + (size_t)(b * COUT + cog * CO_BLK) * OPLANE
                                + (size_t)oh * OSTR + ow + OPADH;
#pragma unroll
                for (int c = 0; c < CO_BLK; c++) {
                    float v = acc[s][py * 2 + px][c];
                    if (DO_TANH) v = tanhf(v);
                    else v = (v >= 0.f) ? v : LRELU * v;
                    ob[(size_t)c * OPLANE] = v;
                }
            }
        }
    }
}

// ======================= VQ argmin (split via kofs) =========================
__global__ __launch_bounds__(256)
void vq_argmin_k(const float* __restrict__ lat, const float* __restrict__ cb,
                 const float* __restrict__ hcbn,
                 unsigned long long* __restrict__ keys, int kofs) {
    const int pb = blockIdx.x;
    if (pb >= 225) return;
    __shared__ float4 scb4[1024];
    __shared__ float  shn[64];
    const int tid = threadIdx.x;
    const int dq  = tid & 3;
    const int pg  = tid >> 2;
    const int kbase = (blockIdx.y + kofs) * 64;
    const int posbase = pb * 256;

    const float4* src = (const float4*)(cb + (size_t)kbase * 64);
#pragma unroll
    for (int i = 0; i < 4; i++) scb4[tid + 256 * i] = src[tid + 256 * i];
    if (tid < 64) shn[tid] = hcbn[kbase + tid];

    float l[4][16];
    int   pidx[4];
#pragma unroll
    for (int j = 0; j < 4; j++) {
        int pos = posbase + pg + 64 * j;
        pidx[j] = pos;
        int b = pos / 900, p = pos - b * 900;
        int oh = p / 30, ow = p - oh * 30;
        int pp = 33 + oh * 32 + ow;
        const float* lb = lat + ((size_t)b * 64 + dq * 16) * 1024 + pp;
#pragma unroll
        for (int i = 0; i < 16; i++) l[j][i] = lb[i * 1024];
    }
    __syncthreads();

    float best[4] = {3.4e38f, 3.4e38f, 3.4e38f, 3.4e38f};
    int   bi[4]   = {0, 0, 0, 0};
#pragma unroll 2
    for (int k0 = 0; k0 < 64; k0++) {
        float4 c0 = scb4[k0 * 16 + dq * 4 + 0];
        float4 c1 = scb4[k0 * 16 + dq * 4 + 1];
        float4 c2 = scb4[k0 * 16 + dq * 4 + 2];
        float4 c3 = scb4[k0 * 16 + dq * 4 + 3];
        float hn = shn[k0];
#pragma unroll
        for (int j = 0; j < 4; j++) {
            float dot = 0.f;
            dot = fmaf(l[j][0],  c0.x, dot); dot = fmaf(l[j][1],  c0.y, dot);
            dot = fmaf(l[j][2],  c0.z, dot); dot = fmaf(l[j][3],  c0.w, dot);
            dot = fmaf(l[j][4],  c1.x, dot); dot = fmaf(l[j][5],  c1.y, dot);
            dot = fmaf(l[j][6],  c1.z, dot); dot = fmaf(l[j][7],  c1.w, dot);
            dot = fmaf(l[j][8],  c2.x, dot); dot = fmaf(l[j][9],  c2.y, dot);
            dot = fmaf(l[j][10], c2.z, dot); dot = fmaf(l[j][11], c2.w, dot);
            dot = fmaf(l[j][12], c3.x, dot); dot = fmaf(l[j][13], c3.y, dot);
            dot = fmaf(l[j][14], c3.z, dot); dot = fmaf(l[j][15], c3.w, dot);
            float full = dot + __shfl_xor(dot, 1);
            full += __shfl_xor(full, 2);
            float score = hn - full;
            if (score < best[j]) { best[j] = score; bi[j] = kbase + k0; }
        }
    }
    if (dq == 0) {
#pragma unroll
        for (int j = 0; j < 4; j++) {
            unsigned u = __float_as_uint(best[j]);
            u = ((int)u < 0) ? ~u : (u | 0x80000000u);
            unsigned long long key = ((unsigned long long)u << 32) | (unsigned)bi[j];
            atomicMin(&keys[pidx[j]], key);
        }
    }
}

// ======================= VQ finalize: idx-map + loss (no z materialization) =
__global__ __launch_bounds__(256)
void vq_finalize_k(const float* __restrict__ lat, const float* __restrict__ cb,
                   const unsigned long long* __restrict__ keys,
                   int* __restrict__ idxm, float* __restrict__ loss_acc, int B) {
    int gid = blockIdx.x * 256 + threadIdx.x;
    const int N = B * 900;
    float myloss = 0.f;
    if (gid < N) {
        int b = gid / 900, p = gid - b * 900;
        int oh = p / 30, ow = p - oh * 30;
        int pp = 33 + oh * 32 + ow;
        int idx = (int)(unsigned)(keys[gid] & 0xFFFFFFFFull);
        idxm[b * 1024 + pp] = idx;
        const float4* crow = (const float4*)(cb + (size_t)idx * 64);
        const float* lrow = lat + (size_t)b * 64 * 1024 + pp;
#pragma unroll
        for (int i = 0; i < 16; i++) {
            float4 cv = crow[i];
            float lv0 = lrow[(4 * i + 0) * 1024];
            float lv1 = lrow[(4 * i + 1) * 1024];
            float lv2 = lrow[(4 * i + 2) * 1024];
            float lv3 = lrow[(4 * i + 3) * 1024];
            float d0 = cv.x - lv0, d1 = cv.y - lv1, d2 = cv.z - lv2, d3 = cv.w - lv3;
            myloss = fmaf(d0, d0, myloss);
            myloss = fmaf(d1, d1, myloss);
            myloss = fmaf(d2, d2, myloss);
            myloss = fmaf(d3, d3, myloss);
        }
    }
    __shared__ float red[256];
    red[threadIdx.x] = myloss;
    __syncthreads();
    for (int s = 128; s > 0; s >>= 1) {
        if ((int)threadIdx.x < s) red[threadIdx.x] += red[threadIdx.x + s];
        __syncthreads();
    }
    if (threadIdx.x == 0) atomicAdd(loss_acc, red[0]);
}

static inline int nblk(long long total) { return (int)((total + 255) / 256); }

extern "C" void kernel_launch(void* const* d_in, const int* in_sizes, int n_in,
                              void* d_out, int out_size, void* d_ws, size_t ws_size,
                              hipStream_t stream) {
    const float* x   = (const float*)d_in[0];
    const float* ew1 = (const float*)d_in[1];  const float* eb1 = (const float*)d_in[2];
    const float* ew2 = (const float*)d_in[3];  const float* eb2 = (const float*)d_in[4];
    const float* ew3 = (const float*)d_in[5];  const float* eb3 = (const float*)d_in[6];
    const float* ew4 = (const float*)d_in[7];  const float* eb4 = (const float*)d_in[8];
    const float* ew5 = (const float*)d_in[9];  const float* eb5 = (const float*)d_in[10];
    const float* dw1 = (const float*)d_in[11]; const float* db1 = (const float*)d_in[12];
    const float* dw2 = (const float*)d_in[13]; const float* db2 = (const float*)d_in[14];
    const float* dw3 = (const float*)d_in[15]; const float* db3 = (const float*)d_in[16];
    const float* dw4 = (const float*)d_in[17]; const float* db4 = (const float*)d_in[18];
    const float* cb  = (const float*)d_in[19];
    float* out = (float*)d_out;

    const int B = in_sizes[0] / (256 * 256);   // 64
    const int N = B * 900;                     // 57600

    char* ws = (char*)d_ws;
    float* A  = (float*)(ws);
    float* Bb = (float*)(ws + 34873344);
    unsigned long long* keys = (unsigned long long*)(ws + 51904512);
    float* hcbn = (float*)(ws + 52365312);
    float* loss = (float*)(ws + 52367360);
    float* wtb  = (float*)(ws + 52367616);
    int*   idxm = (int*)(ws + 52572160);       // 64x1024 ints = 262144 B
    float* U    = (float*)(ws + 52834304);     // 513*9*32 floats = 590976 B
    float* ew1t = wtb;          float* ew2t = wtb + 128;
    float* ew3t = wtb + 2176;   float* ew4t = wtb + 10368;
    float* ew5t = wtb + 19584;  float* dw1t = wtb + 21632;
    float* dw2t = wtb + 40064;  float* dw3t = wtb + 48256;
    float* dw4t = wtb + 50304;

    prep_k<<<nblk(50945 + N + 64 * 124), 256, 0, stream>>>(
        ew1, ew2, ew3, ew4, ew5, dw1, dw2, dw3, dw4, wtb,
        cb, hcbn, keys, loss, idxm, N);
    ubuild_k<<<nblk(513 * 288), 256, 0, stream>>>(dw1t, cb, U);

    // ---- encoder ----
    convs2_k<1, 8, 8, 256, 256, 127, 127, 127 * 128, 128, 0, 4, 8, 32, 0>
        <<<dim3(B, 1, 32), 256, 0, stream>>>(x, ew1t, eb1, A);
    convs2_k<8, 16, 4, 127, 128, 62, 62, 62 * 64, 64, 0, 2, 4, 8, 0>
        <<<dim3(B, 4, 8), 256, 0, stream>>>(A, ew2t, eb2, Bb);
    // e3 + A-frame zeroing (A padded frame needed by e4's 3x3 reads)
    convs2_k<16, 32, 4, 62, 64, 30, 30, 1024, 32, 1, 1, 2, 2, 32>
        <<<dim3(B, 8, 18), 256, 0, stream>>>(Bb, ew3t, eb3, A);
    conv3_k<32, 32, 4, 1024, 32, 1, 1, false>
        <<<dim3(B, 8, 2), 256, 0, stream>>>(A, ew4t, eb4, Bb);
    conv1_k<32, 64, 4><<<dim3(B, 16, 1), 256, 0, stream>>>(Bb, ew5t, eb5, A);

    // ---- VQ ----
    vq_argmin_k<<<dim3(232, 4), 256, 0, stream>>>(A, cb, hcbn, keys, 0);
    vq_argmin_k<<<dim3(232, 4), 256, 0, stream>>>(A, cb, hcbn, keys, 4);
    vq_finalize_k<<<nblk(N), 256, 0, stream>>>(A, cb, keys, idxm, loss, B);

    // ---- decoder ----
    // d1 via code table: idxmap -> A [64,32,30,(34)]
    d1tab_k<<<dim3(B, 2, 4), 256, 0, stream>>>(idxm, U, db1, A);
    // d2: A -> Bb [64,16,63,(66)], + side-col zeroing of d2out
    convtf_k<32, 16, 4, 30, 34, 63, 63, 63 * 66, 66, 1, 1, 2,
             16, 63, 66, 63, false, false>
        <<<dim3(B, 1, 20), 256, 0, stream>>>(A, dw2t, db2, Bb, nullptr, nullptr);
    // d3: Bb -> A [64,8,129,(132)], + side-col zeroing of d3out
    convtf_k<16, 8, 8, 63, 66, 129, 129, 129 * 132, 132, 1, 3, 15,
             8, 129, 132, 129, false, false>
        <<<dim3(B, 1, 28), 256, 0, stream>>>(Bb, dw3t, db3, A, nullptr, nullptr);
    // d4: A -> out [64,1,260,260], tanh, + loss-final slice
    convtf_k<8, 1, 1, 129, 132, 260, 260, 67600, 260, 0, 5, 45,
             0, 1, 1, 0, true, true>
        <<<dim3(B, 1, 46), 256, 0, stream>>>(A, dw4t, db4, out, loss,
                                             out + (out_size - 1));
}

// Round 15
// 407.275 us; speedup vs baseline: 3.5650x; 1.0314x over previous
//
#include <hip/hip_runtime.h>
#include <hip/hip_bf16.h>
#include <math.h>

#define LRELU 0.01f

// ---------- vectorized LDS weight fetch ----------
template<int NW>
__device__ __forceinline__ void ldw(const float* p, float* w) {
    if constexpr (NW % 4 == 0) {
#pragma unroll
        for (int u = 0; u < NW / 4; u++) {
            float4 v = *(const float4*)(p + 4 * u);
            w[4*u] = v.x; w[4*u+1] = v.y; w[4*u+2] = v.z; w[4*u+3] = v.w;
        }
    } else {
#pragma unroll
        for (int c = 0; c < NW; c++) w[c] = p[c];
    }
}

// ======================= fused prep =======================
__device__ __forceinline__ void wfwd(const float* s, float* d, int CIN, int COUT,
                                     int KK, int i) {
    int co = i / (CIN * KK); int r = i - co * CIN * KK;
    int ci = r / KK; int t = r - ci * KK;
    d[(ci * KK + t) * COUT + co] = s[i];
}
__device__ __forceinline__ void wtr(const float* s, float* d, int CIN, int COUT,
                                    int KK, int i) {
    int ci = i / (COUT * KK); int r = i - ci * COUT * KK;
    int co = r / KK; int t = r - co * KK;
    d[(t * CIN + ci) * COUT + co] = s[i];
}
__global__ __launch_bounds__(256)
void prep_k(const float* e1, const float* e2, const float* e3, const float* e4,
            const float* e5, const float* d1, const float* d2, const float* d3,
            const float* d4, float* w, const float* cbp, float* hcbn,
            unsigned long long* keys, float* loss, int* idxm, int N) {
    int i = blockIdx.x * 256 + threadIdx.x;
    if      (i < 128)   wfwd(e1, w + 0,     1,  8, 16, i);
    else if (i < 2176)  wfwd(e2, w + 128,   8, 16, 16, i - 128);
    else if (i < 10368) wfwd(e3, w + 2176, 16, 32, 16, i - 2176);
    else if (i < 19584) wfwd(e4, w + 10368, 32, 32, 9, i - 10368);
    else if (i < 21632) wfwd(e5, w + 19584, 32, 64, 1, i - 19584);
    else if (i < 40064) wfwd(d1, w + 21632, 64, 32, 9, i - 21632);
    else if (i < 48256) wtr (d2, w + 40064, 32, 16, 16, i - 40064);
    else if (i < 50304) wtr (d3, w + 48256, 16,  8, 16, i - 48256);
    else if (i < 50432) wtr (d4, w + 50304,  8,  1, 16, i - 50304);
    else if (i < 50944) {
        int k = i - 50432;
        const float* c = cbp + k * 64;
        float s = 0.f;
#pragma unroll
        for (int d = 0; d < 64; d++) s = fmaf(c[d], c[d], s);
        hcbn[k] = 0.5f * s;
    } else if (i < 50944 + N) {
        keys[i - 50944] = 0xFFFFFFFFFFFFFFFFull;
    } else if (i == 50944 + N) {
        loss[0] = 0.f;
    } else if (i < 50945 + N + 64 * 124) {
        // idx-map padding frame = sentinel 512 (U[512] == 0)
        int j = i - (50945 + N);
        int b2 = j / 124, s = j - b2 * 124;
        int r, c;
        if (s < 32)      { r = 0;  c = s; }
        else if (s < 64) { r = 31; c = s - 32; }
        else { int u = s - 64; r = 1 + (u >> 1); c = (u & 1) * 31; }
        idxm[b2 * 1024 + r * 32 + c] = 512;
    }
}

// ======================= U table =======================
__global__ __launch_bounds__(256)
void ubuild_k(const float* __restrict__ w, const float* __restrict__ cb,
              float* __restrict__ U) {
    int g = blockIdx.x * 256 + threadIdx.x;
    if (g >= 513 * 288) return;
    if (g >= 512 * 288) { U[g] = 0.f; return; }
    int k = g / 288, rem = g - k * 288;
    const float* cr = cb + k * 64;
    float s = 0.f;
#pragma unroll 4
    for (int ci = 0; ci < 64; ci++)
        s = fmaf(w[ci * 288 + rem], cr[ci], s);
    U[g] = s;
}

// ======================= k4 s2 forward conv (+frame-zero slices) ============
template<int CIN, int COUT, int CO_BLK, int HIN, int ISTR, int HOUT, int WOUT,
         int OPLANE, int OSTR, int OPAD, int CB, int RB, int ZCONV, int ZF_CH>
__global__ __launch_bounds__(256)
void convs2_k(const float* __restrict__ in, const float* __restrict__ wt,
              const float* __restrict__ bias, float* __restrict__ out) {
    const int b = blockIdx.x, cog = blockIdx.y, tid = threadIdx.x;
    if (ZF_CH > 0 && (int)blockIdx.z >= ZCONV) {
        if (cog != 0) return;
        int i = ((int)blockIdx.z - ZCONV) * 256 + tid;
        if (i >= ZF_CH * 124) return;
        int ch = i / 124, s = i - ch * 124;
        int r, c;
        if (s < 32)      { r = 0;  c = s; }
        else if (s < 64) { r = 31; c = s - 32; }
        else { int u = s - 64; r = 1 + (u >> 1); c = (u & 1) * 31; }
        out[(size_t)(b * ZF_CH + ch) * 1024 + r * 32 + c] = 0.f;
        return;
    }
    __shared__ __align__(16) float lw[CIN * 16 * CO_BLK];
    for (int i = tid; i < CIN * 16 * CO_BLK; i += 256) {
        int row = i / CO_BLK, c = i - row * CO_BLK;
        lw[i] = wt[row * COUT + cog * CO_BLK + c];
    }
    __syncthreads();

    const int tz = blockIdx.z;
    const int cbi = tz / RB, rb = tz - cbi * RB;
    const int tx = tid & 15, ty = tid >> 4;
    const int ow0 = (cbi * 16 + tx) * 2;
    const int oh  = rb * 16 + ty;
    if (oh >= HOUT || ow0 >= WOUT) return;
    const bool p1v = (ow0 + 1) < WOUT;

    float acc[CO_BLK][2];
#pragma unroll
    for (int c = 0; c < CO_BLK; c++) {
        float bv = bias[cog * CO_BLK + c];
        acc[c][0] = bv; acc[c][1] = bv;
    }
    const float* inb = in + ((size_t)(b * CIN) * HIN + oh * 2) * ISTR + ow0 * 2;
#pragma unroll 2
    for (int ci = 0; ci < CIN; ci++) {
        const float* r = inb + (size_t)ci * HIN * ISTR;
        float4 a4[4]; float2 b2[4];
#pragma unroll
        for (int kh = 0; kh < 4; kh++) {
            a4[kh] = *(const float4*)(r + kh * ISTR);
            b2[kh] = p1v ? *(const float2*)(r + kh * ISTR + 4) : make_float2(0.f, 0.f);
        }
        const float* wr = lw + ci * 16 * CO_BLK;
#pragma unroll
        for (int kh = 0; kh < 4; kh++) {
            float x0[4] = {a4[kh].x, a4[kh].y, a4[kh].z, a4[kh].w};
            float x1[4] = {a4[kh].z, a4[kh].w, b2[kh].x, b2[kh].y};
#pragma unroll
            for (int kw = 0; kw < 4; kw++) {
                float wv[CO_BLK];
                ldw<CO_BLK>(wr + (kh * 4 + kw) * CO_BLK, wv);
#pragma unroll
                for (int c = 0; c < CO_BLK; c++) {
                    acc[c][0] = fmaf(x0[kw], wv[c], acc[c][0]);
                    acc[c][1] = fmaf(x1[kw], wv[c], acc[c][1]);
                }
            }
        }
    }
    float* ob = out + (size_t)(b * COUT + cog * CO_BLK) * OPLANE
                    + (oh + OPAD) * OSTR + ow0 + OPAD;
#pragma unroll
    for (int c = 0; c < CO_BLK; c++) {
        float v0 = acc[c][0]; v0 = (v0 >= 0.f) ? v0 : LRELU * v0;
        ob[(size_t)c * OPLANE] = v0;
        if (p1v) {
            float v1 = acc[c][1]; v1 = (v1 >= 0.f) ? v1 : LRELU * v1;
            ob[(size_t)c * OPLANE + 1] = v1;
        }
    }
}

// ======================= k3 s1 p1 conv =======================
template<int CIN, int COUT, int CO_BLK, int OPLANE, int OSTR, int OPADH, int OPADV,
         bool ZSIDE>
__global__ __launch_bounds__(256)
void conv3_k(const float* __restrict__ in, const float* __restrict__ wt,
             const float* __restrict__ bias, float* __restrict__ out) {
    const int b = blockIdx.x, cog = blockIdx.y, tid = threadIdx.x;
    __shared__ __align__(16) float lw[CIN * 9 * CO_BLK];
    for (int i = tid; i < CIN * 9 * CO_BLK; i += 256) {
        int row = i / CO_BLK, c = i - row * CO_BLK;
        lw[i] = wt[row * COUT + cog * CO_BLK + c];
    }
    __syncthreads();

    const int rb = blockIdx.z;
    const int tx = tid & 15, ty = tid >> 4;
    const int r = rb * 16 + ty;
    if (r >= 30) return;
    const int ow0 = tx * 2;
    if (tx == 15) {
        if (ZSIDE) {
#pragma unroll
            for (int c = 0; c < CO_BLK; c++) {
                float* base = out + (size_t)(b * COUT + cog * CO_BLK + c) * OPLANE
                                  + (r + OPADV) * OSTR;
                base[0] = 0.f; base[31] = 0.f; base[32] = 0.f;
            }
        }
        return;
    }
    float acc[CO_BLK][2];
#pragma unroll
    for (int c = 0; c < CO_BLK; c++) {
        float bv = bias[cog * CO_BLK + c];
        acc[c][0] = bv; acc[c][1] = bv;
    }
    const float* inb = in + ((size_t)(b * CIN) * 32 + r) * 32 + ow0;
#pragma unroll 2
    for (int ci = 0; ci < CIN; ci++) {
        const float* rr = inb + (size_t)ci * 1024;
        float2 A[3], Bv[3];
#pragma unroll
        for (int kh = 0; kh < 3; kh++) {
            A[kh]  = *(const float2*)(rr + kh * 32);
            Bv[kh] = *(const float2*)(rr + kh * 32 + 2);
        }
        const float* wr = lw + ci * 9 * CO_BLK;
#pragma unroll
        for (int kh = 0; kh < 3; kh++) {
            float x0[3] = {A[kh].x, A[kh].y, Bv[kh].x};
            float x1[3] = {A[kh].y, Bv[kh].x, Bv[kh].y};
#pragma unroll
            for (int kw = 0; kw < 3; kw++) {
                float wv[CO_BLK];
                ldw<CO_BLK>(wr + (kh * 3 + kw) * CO_BLK, wv);
#pragma unroll
                for (int c = 0; c < CO_BLK; c++) {
                    acc[c][0] = fmaf(x0[kw], wv[c], acc[c][0]);
                    acc[c][1] = fmaf(x1[kw], wv[c], acc[c][1]);
                }
            }
        }
    }
    float* ob = out + (size_t)(b * COUT + cog * CO_BLK) * OPLANE
                    + (r + OPADV) * OSTR + ow0 + OPADH;
#pragma unroll
    for (int c = 0; c < CO_BLK; c++) {
        float v0 = acc[c][0]; v0 = (v0 >= 0.f) ? v0 : LRELU * v0;
        float v1 = acc[c][1]; v1 = (v1 >= 0.f) ? v1 : LRELU * v1;
        ob[(size_t)c * OPLANE] = v0;
        ob[(size_t)c * OPLANE + 1] = v1;
    }
}

// ======================= 1x1 conv =======================
template<int CIN, int COUT, int CO_BLK>
__global__ __launch_bounds__(256)
void conv1_k(const float* __restrict__ in, const float* __restrict__ wt,
             const float* __restrict__ bias, float* __restrict__ out) {
    __shared__ __align__(16) float lw[CIN * CO_BLK];
    const int b = blockIdx.x, cog = blockIdx.y;
    for (int i = threadIdx.x; i < CIN * CO_BLK; i += 256) {
        int row = i / CO_BLK, c = i - row * CO_BLK;
        lw[i] = wt[row * COUT + cog * CO_BLK + c];
    }
    __syncthreads();

    const int px4 = threadIdx.x * 4;
    float acc[CO_BLK][4];
#pragma unroll
    for (int c = 0; c < CO_BLK; c++) {
        float bv = bias[cog * CO_BLK + c];
        acc[c][0] = bv; acc[c][1] = bv; acc[c][2] = bv; acc[c][3] = bv;
    }
#pragma unroll 4
    for (int ci = 0; ci < CIN; ci++) {
        float4 x = *(const float4*)(in + (size_t)(b * CIN + ci) * 1024 + px4);
        float wv[CO_BLK];
        ldw<CO_BLK>(lw + ci * CO_BLK, wv);
#pragma unroll
        for (int c = 0; c < CO_BLK; c++) {
            acc[c][0] = fmaf(x.x, wv[c], acc[c][0]);
            acc[c][1] = fmaf(x.y, wv[c], acc[c][1]);
            acc[c][2] = fmaf(x.z, wv[c], acc[c][2]);
            acc[c][3] = fmaf(x.w, wv[c], acc[c][3]);
        }
    }
#pragma unroll
    for (int c = 0; c < CO_BLK; c++) {
        float4 v;
        v.x = (acc[c][0] >= 0.f) ? acc[c][0] : LRELU * acc[c][0];
        v.y = (acc[c][1] >= 0.f) ? acc[c][1] : LRELU * acc[c][1];
        v.z = (acc[c][2] >= 0.f) ? acc[c][2] : LRELU * acc[c][2];
        v.w = (acc[c][3] >= 0.f) ? acc[c][3] : LRELU * acc[c][3];
        *(float4*)(out + (size_t)(b * COUT + cog * CO_BLK + c) * 1024 + px4) = v;
    }
}

// ======================= d1 via code table (pad-2 output layout) ============
// out [64,32,30,(34)]: data cols 2..31, zero cols {1,32,33}.
__global__ __launch_bounds__(256)
void d1tab_k(const int* __restrict__ idxm, const float* __restrict__ U,
             const float* __restrict__ bias, float* __restrict__ out) {
    const int b = blockIdx.x, cog = blockIdx.y, rt = blockIdx.z;
    const int tx = threadIdx.x & 31, ty = threadIdx.x >> 5;
    const int r = rt * 8 + ty;
    if (r >= 30) return;
    if (tx >= 30) {
        if (tx == 31) {
#pragma unroll
            for (int c = 0; c < 16; c++) {
                float* base = out + (size_t)(b * 32 + cog * 16 + c) * 1020 + r * 34;
                base[1] = 0.f; base[32] = 0.f; base[33] = 0.f;
            }
        }
        return;
    }
    const int* im = idxm + b * 1024 + r * 32 + tx;
    float acc[16];
#pragma unroll
    for (int c = 0; c < 16; c++) acc[c] = bias[cog * 16 + c];
#pragma unroll
    for (int kh = 0; kh < 3; kh++) {
        int i0 = im[kh * 32 + 0];
        int i1 = im[kh * 32 + 1];
        int i2 = im[kh * 32 + 2];
        const float4* u0 = (const float4*)(U + ((size_t)i0 * 9 + kh * 3 + 0) * 32 + cog * 16);
        const float4* u1 = (const float4*)(U + ((size_t)i1 * 9 + kh * 3 + 1) * 32 + cog * 16);
        const float4* u2 = (const float4*)(U + ((size_t)i2 * 9 + kh * 3 + 2) * 32 + cog * 16);
#pragma unroll
        for (int q = 0; q < 4; q++) {
            float4 a = u0[q], bb = u1[q], cc = u2[q];
            acc[4*q+0] += (a.x + bb.x) + cc.x;
            acc[4*q+1] += (a.y + bb.y) + cc.y;
            acc[4*q+2] += (a.z + bb.z) + cc.z;
            acc[4*q+3] += (a.w + bb.w) + cc.w;
        }
    }
    float* ob = out + (size_t)(b * 32 + cog * 16) * 1020 + r * 34 + tx + 2;
#pragma unroll
    for (int c = 0; c < 16; c++) {
        float v = acc[c]; v = (v >= 0.f) ? v : LRELU * v;
        ob[(size_t)c * 1020] = v;
    }
}

// ======================= parity-fused convT k4 s2 (aligned float2 stores) ===
template<int CIN, int COUT, int CO_BLK, int HIN, int ISTR, int HOUT, int WOUT,
         int OPLANE, int OSTR, int OPADH, int NTX, int NT,
         int ZS_CH, int ZS_H, int ZS_STR, int ZC0, int ZC1, int ZC2,
         bool DO_TANH, bool DO_LOSS>
__global__ __launch_bounds__(256)
void convtf_k(const float* __restrict__ in, const float* __restrict__ wt,
              const float* __restrict__ bias, float* __restrict__ out,
              const float* __restrict__ loss, float* __restrict__ losstgt) {
    const int b = blockIdx.x, tid = threadIdx.x;
    const int NCOG = COUT / CO_BLK;
    int zz = blockIdx.z;
    if (zz >= NCOG * NT) {
        if (DO_LOSS) {
            if (b == 0 && tid == 0)
                losstgt[0] = 1.25f * loss[0] / (57600.f * 64.f);
            return;
        }
        int i = (zz - NCOG * NT) * 256 + tid;
        if (i >= ZS_CH * ZS_H * 3) return;
        int ch = i / (ZS_H * 3); int u = i - ch * ZS_H * 3;
        int r = u / 3, c3 = u - r * 3;
        int col = (c3 == 0) ? ZC0 : (c3 == 1) ? ZC1 : ZC2;
        out[((size_t)(b * ZS_CH + ch) * ZS_H + r) * ZS_STR + col] = 0.f;
        return;
    }
    const int cog = zz / NT, tile = zz - cog * NT;
    const int tlx = tile % NTX, tly = tile / NTX;

    __shared__ __align__(16) float lw[16 * CIN * CO_BLK];
    for (int i = tid; i < 16 * CIN * CO_BLK; i += 256) {
        int aq = i / (CIN * 4 * CO_BLK);
        int r1 = i - aq * (CIN * 4 * CO_BLK);
        int ci = r1 / (4 * CO_BLK);
        int u  = r1 - ci * (4 * CO_BLK);
        int pp = u / CO_BLK, c = u - pp * CO_BLK;
        int a = aq >> 1, q = aq & 1, py = pp >> 1, px = pp & 1;
        int tap = (py + 2 * a) * 4 + px + 2 * q;
        lw[i] = wt[((size_t)tap * CIN + ci) * COUT + cog * CO_BLK + c];
    }
    __syncthreads();

    const int SX = (WOUT + 1) >> 1, SY = (HOUT + 1) >> 1;
    const int sx0 = tlx * 32 + (tid & 15);
    const int sx1 = sx0 + 16;
    const int sy  = tly * 16 + (tid >> 4);
    const bool v0 = sx0 < SX, v1 = sx1 < SX;
    if (sy >= SY || !(v0 || v1)) return;

    const bool rvA = (sy < HIN);
    const bool rvB = (sy >= 1) && (sy <= HIN);

    float acc[2][4][CO_BLK];
#pragma unroll
    for (int s = 0; s < 2; s++)
#pragma unroll
        for (int o = 0; o < 4; o++)
#pragma unroll
            for (int c = 0; c < CO_BLK; c++)
                acc[s][o][c] = bias[cog * CO_BLK + c];

    const float* base = in + (size_t)(b * CIN) * HIN * ISTR;
#pragma unroll 2
    for (int ci = 0; ci < CIN; ci++) {
        const float* rowA = base + (size_t)ci * HIN * ISTR + (size_t)sy * ISTR;
        const float* rowB = rowA - ISTR;
        float rA0x = 0.f, rA0y = 0.f, rA1x = 0.f, rA1y = 0.f;
        float rB0x = 0.f, rB0y = 0.f, rB1x = 0.f, rB1y = 0.f;
        if (rvA) {
            if (v0) { rA0x = rowA[sx0]; rA0y = rowA[sx0 + 1]; }
            if (v1) { rA1x = rowA[sx1]; rA1y = rowA[sx1 + 1]; }
        }
        if (rvB) {
            if (v0) { rB0x = rowB[sx0]; rB0y = rowB[sx0 + 1]; }
            if (v1) { rB1x = rowB[sx1]; rB1y = rowB[sx1 + 1]; }
        }
#pragma unroll
        for (int a = 0; a < 2; a++) {
#pragma unroll
            for (int q = 0; q < 2; q++) {
                float iv0 = q ? (a ? rB0x : rA0x) : (a ? rB0y : rA0y);
                float iv1 = q ? (a ? rB1x : rA1x) : (a ? rB1y : rA1y);
                const float* wp = lw + (size_t)((a * 2 + q) * CIN + ci) * (4 * CO_BLK);
                float wv[4 * CO_BLK];
                ldw<4 * CO_BLK>(wp, wv);
#pragma unroll
                for (int o = 0; o < 4; o++)
#pragma unroll
                    for (int c = 0; c < CO_BLK; c++) {
                        acc[0][o][c] = fmaf(iv0, wv[o * CO_BLK + c], acc[0][o][c]);
                        acc[1][o][c] = fmaf(iv1, wv[o * CO_BLK + c], acc[1][o][c]);
                    }
            }
        }
    }
#pragma unroll
    for (int s = 0; s < 2; s++) {
        if (s ? !v1 : !v0) continue;
        const int sxx = s ? sx1 : sx0;
        const int ow = 2 * sxx;
        const bool full = (ow + 1) < WOUT;
#pragma unroll
        for (int py = 0; py < 2; py++) {
            int oh = 2 * sy + py;
            if (oh >= HOUT) continue;
            float* ob = out + (size_t)(b * COUT + cog * CO_BLK) * OPLANE
                            + (size_t)oh * OSTR + ow + OPADH;
#pragma unroll
            for (int c = 0; c < CO_BLK; c++) {
                float va = acc[s][py * 2 + 0][c];
                float vb = acc[s][py * 2 + 1][c];
                if (DO_TANH) { va = tanhf(va); vb = tanhf(vb); }
                else {
                    va = (va >= 0.f) ? va : LRELU * va;
                    vb = (vb >= 0.f) ? vb : LRELU * vb;
                }
                if ((OPADH & 1) == 0 && full) {
                    *(float2*)(ob + (size_t)c * OPLANE) = make_float2(va, vb);
                } else {
                    ob[(size_t)c * OPLANE] = va;
                    if (full) ob[(size_t)c * OPLANE + 1] = vb;
                }
            }
        }
    }
}

// ======================= VQ argmin =======================
__global__ __launch_bounds__(256)
void vq_argmin_k(const float* __restrict__ lat, const float* __restrict__ cb,
                 const float* __restrict__ hcbn,
                 unsigned long long* __restrict__ keys) {
    const int pb = blockIdx.x;
    if (pb >= 225) return;
    __shared__ float4 scb4[1024];
    __shared__ float  shn[64];
    const int tid = threadIdx.x;
    const int dq  = tid & 3;
    const int pg  = tid >> 2;
    const int kbase = blockIdx.y * 64;
    const int posbase = pb * 256;

    const float4* src = (const float4*)(cb + (size_t)kbase * 64);
#pragma unroll
    for (int i = 0; i < 4; i++) scb4[tid + 256 * i] = src[tid + 256 * i];
    if (tid < 64) shn[tid] = hcbn[kbase + tid];

    float l[4][16];
    int   pidx[4];
#pragma unroll
    for (int j = 0; j < 4; j++) {
        int pos = posbase + pg + 64 * j;
        pidx[j] = pos;
        int b = pos / 900, p = pos - b * 900;
        int oh = p / 30, ow = p - oh * 30;
        int pp = 33 + oh * 32 + ow;
        const float* lb = lat + ((size_t)b * 64 + dq * 16) * 1024 + pp;
#pragma unroll
        for (int i = 0; i < 16; i++) l[j][i] = lb[i * 1024];
    }
    __syncthreads();

    float best[4] = {3.4e38f, 3.4e38f, 3.4e38f, 3.4e38f};
    int   bi[4]   = {0, 0, 0, 0};
#pragma unroll 2
    for (int k0 = 0; k0 < 64; k0++) {
        float4 c0 = scb4[k0 * 16 + dq * 4 + 0];
        float4 c1 = scb4[k0 * 16 + dq * 4 + 1];
        float4 c2 = scb4[k0 * 16 + dq * 4 + 2];
        float4 c3 = scb4[k0 * 16 + dq * 4 + 3];
        float hn = shn[k0];
#pragma unroll
        for (int j = 0; j < 4; j++) {
            float dot = 0.f;
            dot = fmaf(l[j][0],  c0.x, dot); dot = fmaf(l[j][1],  c0.y, dot);
            dot = fmaf(l[j][2],  c0.z, dot); dot = fmaf(l[j][3],  c0.w, dot);
            dot = fmaf(l[j][4],  c1.x, dot); dot = fmaf(l[j][5],  c1.y, dot);
            dot = fmaf(l[j][6],  c1.z, dot); dot = fmaf(l[j][7],  c1.w, dot);
            dot = fmaf(l[j][8],  c2.x, dot); dot = fmaf(l[j][9],  c2.y, dot);
            dot = fmaf(l[j][10], c2.z, dot); dot = fmaf(l[j][11], c2.w, dot);
            dot = fmaf(l[j][12], c3.x, dot); dot = fmaf(l[j][13], c3.y, dot);
            dot = fmaf(l[j][14], c3.z, dot); dot = fmaf(l[j][15], c3.w, dot);
            float full = dot + __shfl_xor(dot, 1);
            full += __shfl_xor(full, 2);
            float score = hn - full;
            if (score < best[j]) { best[j] = score; bi[j] = kbase + k0; }
        }
    }
    if (dq == 0) {
#pragma unroll
        for (int j = 0; j < 4; j++) {
            unsigned u = __float_as_uint(best[j]);
            u = ((int)u < 0) ? ~u : (u | 0x80000000u);
            unsigned long long key = ((unsigned long long)u << 32) | (unsigned)bi[j];
            atomicMin(&keys[pidx[j]], key);
        }
    }
}

// ======================= VQ finalize: idx-map + loss =======================
__global__ __launch_bounds__(256)
void vq_finalize_k(const float* __restrict__ lat, const float* __restrict__ cb,
                   const unsigned long long* __restrict__ keys,
                   int* __restrict__ idxm, float* __restrict__ loss_acc, int B) {
    int gid = blockIdx.x * 256 + threadIdx.x;
    const int N = B * 900;
    float myloss = 0.f;
    if (gid < N) {
        int b = gid / 900, p = gid - b * 900;
        int oh = p / 30, ow = p - oh * 30;
        int pp = 33 + oh * 32 + ow;
        int idx = (int)(unsigned)(keys[gid] & 0xFFFFFFFFull);
        idxm[b * 1024 + pp] = idx;
        const float4* crow = (const float4*)(cb + (size_t)idx * 64);
        const float* lrow = lat + (size_t)b * 64 * 1024 + pp;
#pragma unroll
        for (int i = 0; i < 16; i++) {
            float4 cv = crow[i];
            float lv0 = lrow[(4 * i + 0) * 1024];
            float lv1 = lrow[(4 * i + 1) * 1024];
            float lv2 = lrow[(4 * i + 2) * 1024];
            float lv3 = lrow[(4 * i + 3) * 1024];
            float d0 = cv.x - lv0, d1 = cv.y - lv1, d2 = cv.z - lv2, d3 = cv.w - lv3;
            myloss = fmaf(d0, d0, myloss);
            myloss = fmaf(d1, d1, myloss);
            myloss = fmaf(d2, d2, myloss);
            myloss = fmaf(d3, d3, myloss);
        }
    }
    __shared__ float red[256];
    red[threadIdx.x] = myloss;
    __syncthreads();
    for (int s = 128; s > 0; s >>= 1) {
        if ((int)threadIdx.x < s) red[threadIdx.x] += red[threadIdx.x + s];
        __syncthreads();
    }
    if (threadIdx.x == 0) atomicAdd(loss_acc, red[0]);
}

static inline int nblk(long long total) { return (int)((total + 255) / 256); }

extern "C" void kernel_launch(void* const* d_in, const int* in_sizes, int n_in,
                              void* d_out, int out_size, void* d_ws, size_t ws_size,
                              hipStream_t stream) {
    const float* x   = (const float*)d_in[0];
    const float* ew1 = (const float*)d_in[1];  const float* eb1 = (const float*)d_in[2];
    const float* ew2 = (const float*)d_in[3];  const float* eb2 = (const float*)d_in[4];
    const float* ew3 = (const float*)d_in[5];  const float* eb3 = (const float*)d_in[6];
    const float* ew4 = (const float*)d_in[7];  const float* eb4 = (const float*)d_in[8];
    const float* ew5 = (const float*)d_in[9];  const float* eb5 = (const float*)d_in[10];
    const float* dw1 = (const float*)d_in[11]; const float* db1 = (const float*)d_in[12];
    const float* dw2 = (const float*)d_in[13]; const float* db2 = (const float*)d_in[14];
    const float* dw3 = (const float*)d_in[15]; const float* db3 = (const float*)d_in[16];
    const float* dw4 = (const float*)d_in[17]; const float* db4 = (const float*)d_in[18];
    const float* cb  = (const float*)d_in[19];
    float* out = (float*)d_out;

    const int B = in_sizes[0] / (256 * 256);   // 64
    const int N = B * 900;                     // 57600

    // ---- workspace map (liveness-audited; peak 53.2 MB) ----
    // [0, 34,873,344):  e1out -> e3out -> lat -> d1out -> d3out
    // [34,873,344, 52,420,608): e2out -> e4out -> d2out[64,16,63,68]
    //   (keys/hcbn/idxm tucked at its tail, all dead before d2 writes)
    // [52,420,608+): loss | wtb | U   (alive across decoder; outside both)
    char* ws = (char*)d_ws;
    float* A     = (float*)(ws);
    float* Bb    = (float*)(ws + 34873344);
    float* d2out = (float*)(ws + 34873344);
    float* d3out = (float*)(ws);
    unsigned long long* keys = (unsigned long long*)(ws + 51126272);
    float* hcbn  = (float*)(ws + 51587072);
    int*   idxm  = (int*)(ws + 51589120);
    float* loss  = (float*)(ws + 52420608);
    float* wtb   = (float*)(ws + 52420864);
    float* U     = (float*)(ws + 52622592);
    float* ew1t = wtb;          float* ew2t = wtb + 128;
    float* ew3t = wtb + 2176;   float* ew4t = wtb + 10368;
    float* ew5t = wtb + 19584;  float* dw1t = wtb + 21632;
    float* dw2t = wtb + 40064;  float* dw3t = wtb + 48256;
    float* dw4t = wtb + 50304;

    prep_k<<<nblk(50945 + N + 64 * 124), 256, 0, stream>>>(
        ew1, ew2, ew3, ew4, ew5, dw1, dw2, dw3, dw4, wtb,
        cb, hcbn, keys, loss, idxm, N);
    ubuild_k<<<nblk(513 * 288), 256, 0, stream>>>(dw1t, cb, U);

    // ---- encoder ----
    convs2_k<1, 8, 8, 256, 256, 127, 127, 127 * 128, 128, 0, 4, 8, 32, 0>
        <<<dim3(B, 1, 32), 256, 0, stream>>>(x, ew1t, eb1, A);
    convs2_k<8, 16, 4, 127, 128, 62, 62, 62 * 64, 64, 0, 2, 4, 8, 0>
        <<<dim3(B, 4, 8), 256, 0, stream>>>(A, ew2t, eb2, Bb);
    convs2_k<16, 32, 4, 62, 64, 30, 30, 1024, 32, 1, 1, 2, 2, 32>
        <<<dim3(B, 8, 18), 256, 0, stream>>>(Bb, ew3t, eb3, A);
    conv3_k<32, 32, 4, 1024, 32, 1, 1, false>
        <<<dim3(B, 8, 2), 256, 0, stream>>>(A, ew4t, eb4, Bb);
    conv1_k<32, 64, 4><<<dim3(B, 16, 1), 256, 0, stream>>>(Bb, ew5t, eb5, A);

    // ---- VQ ----
    vq_argmin_k<<<dim3(232, 8), 256, 0, stream>>>(A, cb, hcbn, keys);
    vq_finalize_k<<<nblk(N), 256, 0, stream>>>(A, cb, keys, idxm, loss, B);

    // ---- decoder ----
    // d1 via code table -> A [64,32,30,(34)] pad-2 (lat dead)
    d1tab_k<<<dim3(B, 2, 4), 256, 0, stream>>>(idxm, U, db1, A);
    // d2: A(+1) -> d2out [64,16,63,(68)] pad-2, zero cols {1,65,66}
    convtf_k<32, 16, 4, 30, 34, 63, 63, 63 * 68, 68, 2, 1, 2,
             16, 63, 68, 1, 65, 66, false, false>
        <<<dim3(B, 1, 20), 256, 0, stream>>>(A + 1, dw2t, db2, d2out,
                                             nullptr, nullptr);
    // d3: d2out(+1) -> d3out=ws+0 [64,8,129,(132)] pad-2, zero cols {1,131}
    convtf_k<16, 8, 8, 63, 68, 129, 129, 129 * 132, 132, 2, 3, 15,
             8, 129, 132, 1, 1, 131, false, false>
        <<<dim3(B, 1, 28), 256, 0, stream>>>(d2out + 1, dw3t, db3, d3out,
                                             nullptr, nullptr);
    // d4: d3out(+1) -> out [64,1,260,260], tanh, + loss-final slice
    convtf_k<8, 1, 1, 129, 132, 260, 260, 67600, 260, 0, 5, 45,
             0, 1, 1, 0, 0, 0, true, true>
        <<<dim3(B, 1, 46), 256, 0, stream>>>(d3out + 1, dw4t, db4, out, loss,
                                             out + (out_size - 1));
}